// Round 15
// baseline (3331.847 us; speedup 1.0000x reference)
//
#include <hip/hip_runtime.h>
#include <math.h>

typedef float f32x4 __attribute__((ext_vector_type(4)));
typedef short s16x8 __attribute__((ext_vector_type(8)));
typedef unsigned short u16;

// ---------------------------------------------------------------- helpers
__device__ __forceinline__ float sigmoid_(float x) { return 1.f / (1.f + __expf(-x)); }
__device__ __forceinline__ float tanh_(float x) {
  float e = __expf(-2.f * x);
  return fmaf(2.f, 1.f / (1.f + e), -1.f);
}
__device__ __forceinline__ float softplus_(float x) {
  return (x > 15.f) ? x : log1pf(__expf(x));
}
__device__ __forceinline__ u16 f2bf(float f) {  // RNE fp32->bf16
  unsigned u = __float_as_uint(f);
  u += 0x7fffu + ((u >> 16) & 1u);
  return (u16)(u >> 16);
}
__device__ __forceinline__ float bf2f(u16 u) {
  return __uint_as_float((unsigned)u << 16);
}

// ---------------------------------------------------------------- weight prep
__global__ void prep_lstm_w(const float* __restrict__ Wih0, const float* __restrict__ Whh0,
                            const float* __restrict__ Wih1, const float* __restrict__ Whh1,
                            const float* __restrict__ bih0, const float* __restrict__ bhh0,
                            const float* __restrict__ bih1, const float* __restrict__ bhh1,
                            u16* __restrict__ Wp0, u16* __restrict__ Wp1,
                            float* __restrict__ bs0, float* __restrict__ bs1)
{
  int idx = blockIdx.x * 256 + threadIdx.x;
  if (idx < 20 * 512 * 8) {
    int c = idx >> 12, rem = idx & 4095;
    int col = rem >> 3, e = rem & 7;
    int k = c * 8 + e;
    float v = 0.f;
    if (k < 16) v = Wih0[col * 16 + k];
    else if (k >= 32) v = Whh0[col * 128 + (k - 32)];
    Wp0[idx] = f2bf(v);
  }
  int i1 = idx - 20 * 512 * 8;
  if (i1 >= 0 && i1 < 32 * 512 * 8) {
    int c = i1 >> 12, rem = i1 & 4095;
    int col = rem >> 3, e = rem & 7;
    int k = c * 8 + e;
    float v = (k < 128) ? Wih1[col * 128 + k] : Whh1[col * 128 + (k - 128)];
    Wp1[i1] = f2bf(v);
  }
  int i2 = idx - 52 * 512 * 8;
  if (i2 >= 0 && i2 < 512) bs0[i2] = bih0[i2] + bhh0[i2];
  int i3 = i2 - 512;
  if (i3 >= 0 && i3 < 512) bs1[i3] = bih1[i3] + bhh1[i3];
}

// pack fp32 W[K][C] -> bf16 B-fragments Wp[(k/8)*C + col][8]
__global__ void pack_w(const float* __restrict__ W, u16* __restrict__ Wp, int K, int C) {
  int idx = blockIdx.x * 256 + threadIdx.x;
  if (idx < K * C) {
    int k = idx / C, col = idx % C;
    Wp[((size_t)(k >> 3) * C + col) * 8 + (k & 7)] = f2bf(W[idx]);
  }
}

// pack node-head weights
__global__ void pack_headw(const float* __restrict__ cW1, const float* __restrict__ cb1,
                           const float* __restrict__ cW2, const float* __restrict__ cb2,
                           const float* __restrict__ uW1, const float* __restrict__ ub1,
                           const float* __restrict__ uW2, const float* __restrict__ ub2,
                           u16* __restrict__ cuW1p, float* __restrict__ cub1,
                           u16* __restrict__ cuW2p, float* __restrict__ cub2)
{
  int idx = blockIdx.x * 256 + threadIdx.x;
  if (idx < 128 * 128) {
    int k = idx >> 7, col = idx & 127;
    float v = (col < 64) ? cW1[k * 64 + col] : uW1[k * 64 + (col - 64)];
    cuW1p[((size_t)(k >> 3) * 128 + col) * 8 + (k & 7)] = f2bf(v);
  }
  int j = idx - 128 * 128;
  if (j >= 0 && j < 2048) {
    int ch = j >> 7, rem = j & 127, col = rem >> 3, e = rem & 7;
    int k = ch * 8 + e;
    float v = 0.f;
    if (col < 4 && k < 64) v = cW2[k * 4 + col];
    else if (col == 4 && k >= 64) v = uW2[k - 64];
    cuW2p[j] = f2bf(v);
  }
  int j2 = idx - (128 * 128 + 2048);
  if (j2 >= 0 && j2 < 128) cub1[j2] = (j2 < 64) ? cb1[j2] : ub1[j2 - 64];
  int j3 = j2 - 128;
  if (j3 >= 0 && j3 < 16) cub2[j3] = (j3 < 4) ? cb2[j3] : (j3 == 4 ? ub2[0] : 0.f);
}

// ---------------------------------------------------------------- LSTM epilogue (2 m-groups)
__device__ __forceinline__ void epi2(const f32x4 (&acc)[2][4], f32x4* cs,
    const float (&bs)[4], u16* ldsw, int uoff, int kq, int mh,
    int nodebase, float* hf, int u, int n, bool last)
{
#pragma unroll
  for (int mm = 0; mm < 2; ++mm) {
#pragma unroll
    for (int r = 0; r < 4; ++r) {
      float gi = acc[mm][0][r] + bs[0];
      float gf = acc[mm][1][r] + bs[1];
      float gg = acc[mm][2][r] + bs[2];
      float go = acc[mm][3][r] + bs[3];
      float c = sigmoid_(gf) * cs[mm][r] + sigmoid_(gi) * tanh_(gg);
      cs[mm][r] = c;
      float h = sigmoid_(go) * tanh_(c);
      int node = (mh * 2 + mm) * 16 + kq * 4 + r;
      ldsw[uoff + node * 8] = f2bf(h);
      if (last) {
        int gn = nodebase + node;
        if (gn < n) hf[(size_t)gn * 128 + u] = h;
      }
    }
  }
}

// ---------------------------------------------------------------- LSTM layer 0 (256 thr, 2 blocks/CU)
// 4 waves; wave w owns cols [w*32, w*32+32) via 2 col-groups.
__global__ __launch_bounds__(256, 2) void lstm_l0(
    const float* __restrict__ seq, const u16* __restrict__ Wp0,
    const float* __restrict__ bs0, u16* __restrict__ h0seq,
    int n, int tile0, int ntiles)
{
  __shared__ __align__(16) u16 A0[2 * 20 * 512];
  const int RSZ = 20 * 512;
  const int tid = threadIdx.x;
  const int l = tid & 63;
  const int wv = __builtin_amdgcn_readfirstlane(tid >> 6);   // 0..3
  const int kq = l >> 4;
  const int la = (l & 15) * 8;
  float bsr[2][4];
#pragma unroll
  for (int cg = 0; cg < 2; ++cg)
#pragma unroll
    for (int g = 0; g < 4; ++g)
      bsr[cg][g] = bs0[g * 128 + wv * 32 + cg * 16 + (l & 15)];
  const f32x4 zero4 = {0.f, 0.f, 0.f, 0.f};

  for (int tt = blockIdx.x; tt < ntiles; tt += gridDim.x) {
    const int nodebase = (tile0 + tt) * 64;
    const int nld = min(nodebase + (tid >> 2), n - 1);
    u16* __restrict__ hdst = h0seq + (size_t)tt * 20 * 8192;
    for (int i = tid; i < 18 * 512; i += 256) A0[2 * 512 + i] = 0;
    for (int i = tid; i < 2 * 512; i += 256) A0[RSZ + 2 * 512 + i] = 0;
    {
      int nd = tid >> 2, q = tid & 3;
      f32x4 v = __builtin_nontemporal_load((const f32x4*)(seq + (size_t)nld * 320 + q * 4));
      unsigned d0 = (unsigned)f2bf(v[0]) | ((unsigned)f2bf(v[1]) << 16);
      unsigned d1 = (unsigned)f2bf(v[2]) | ((unsigned)f2bf(v[3]) << 16);
      unsigned* dstp = (unsigned*)&A0[(q >> 1) * 512 + nd * 8 + (q & 1) * 4];
      dstp[0] = d0; dstp[1] = d1;
    }
    f32x4 c0[2][4];
#pragma unroll
    for (int cg = 0; cg < 2; ++cg)
#pragma unroll
      for (int m = 0; m < 4; ++m) c0[cg][m] = zero4;
    __syncthreads();

    for (int t = 0; t < 20; ++t) {
      const int base_r = (t & 1) * RSZ;
      const int base_w = ((t + 1) & 1) * RSZ;
      f32x4 xnext;
      const bool ldx = (t < 19);
      if (ldx) xnext = __builtin_nontemporal_load(
          (const f32x4*)(seq + (size_t)nld * 320 + (t + 1) * 16 + (tid & 3) * 4));
      if (t >= 1) {  // copy out h0(t-1) from read region
#pragma unroll
        for (int k = 0; k < 4; ++k) {
          int j = tid + k * 256;
          s16x8 u0 = *(const s16x8*)&A0[base_r + 2048 + j * 8];
          __builtin_nontemporal_store(u0, (s16x8*)&hdst[(size_t)(t - 1) * 8192 + j * 8]);
        }
      }
#pragma unroll
      for (int cg = 0; cg < 2; ++cg) {
        const int colu = wv * 32 + cg * 16 + (l & 15);
        const int uoff = (4 + (colu >> 3)) * 512 + (colu & 7);
#pragma unroll
        for (int mh = 0; mh < 2; ++mh) {
          f32x4 acc[2][4];
#pragma unroll
          for (int mm = 0; mm < 2; ++mm)
#pragma unroll
            for (int g = 0; g < 4; ++g) acc[mm][g] = zero4;
#pragma unroll
          for (int kc = 0; kc < 5; ++kc) {
            const int ch = kc * 4 + kq;
            s16x8 av[2];
#pragma unroll
            for (int mm = 0; mm < 2; ++mm)
              av[mm] = *(const s16x8*)&A0[base_r + ch * 512 + (mh * 2 + mm) * 128 + la];
#pragma unroll
            for (int g = 0; g < 4; ++g) {
              s16x8 bv = *(const s16x8*)&Wp0[(size_t)ch * 4096 + (g * 128 + colu) * 8];
#pragma unroll
              for (int mm = 0; mm < 2; ++mm)
                acc[mm][g] = __builtin_amdgcn_mfma_f32_16x16x32_bf16(av[mm], bv, acc[mm][g], 0, 0, 0);
            }
          }
          epi2(acc, &c0[cg][mh * 2], bsr[cg], &A0[base_w], uoff, kq, mh, 0, nullptr, colu, 0, false);
        }
      }
      if (ldx) {
        int nd = tid >> 2, q = tid & 3;
        unsigned d0 = (unsigned)f2bf(xnext[0]) | ((unsigned)f2bf(xnext[1]) << 16);
        unsigned d1 = (unsigned)f2bf(xnext[2]) | ((unsigned)f2bf(xnext[3]) << 16);
        unsigned* dstp = (unsigned*)&A0[base_w + (q >> 1) * 512 + nd * 8 + (q & 1) * 4];
        dstp[0] = d0; dstp[1] = d1;
      }
      __syncthreads();
    }
    {  // final: h0(19) in region 0
#pragma unroll
      for (int k = 0; k < 4; ++k) {
        int j = tid + k * 256;
        s16x8 u0 = *(const s16x8*)&A0[2048 + j * 8];
        __builtin_nontemporal_store(u0, (s16x8*)&hdst[(size_t)19 * 8192 + j * 8]);
      }
    }
    __syncthreads();
  }
}

// ---------------------------------------------------------------- LSTM layer 1 (256 thr, 2 blocks/CU)
__global__ __launch_bounds__(256, 2) void lstm_l1(
    const u16* __restrict__ h0seq, const u16* __restrict__ Wp1,
    const float* __restrict__ bs1, float* __restrict__ hfinal,
    int n, int tile0, int ntiles)
{
  __shared__ __align__(16) u16 A1[2 * 32 * 512];
  const int RSZ = 32 * 512;
  const int tid = threadIdx.x;
  const int l = tid & 63;
  const int wv = __builtin_amdgcn_readfirstlane(tid >> 6);
  const int kq = l >> 4;
  const int la = (l & 15) * 8;
  float bsr[2][4];
#pragma unroll
  for (int cg = 0; cg < 2; ++cg)
#pragma unroll
    for (int g = 0; g < 4; ++g)
      bsr[cg][g] = bs1[g * 128 + wv * 32 + cg * 16 + (l & 15)];
  const f32x4 zero4 = {0.f, 0.f, 0.f, 0.f};

  for (int tt = blockIdx.x; tt < ntiles; tt += gridDim.x) {
    const int nodebase = (tile0 + tt) * 64;
    const u16* __restrict__ hsrc = h0seq + (size_t)tt * 20 * 8192;
    for (int i = tid; i < 16 * 512; i += 256) A1[16 * 512 + i] = 0;
#pragma unroll
    for (int k = 0; k < 4; ++k) {
      int j = tid + k * 256;
      s16x8 s0 = __builtin_nontemporal_load((const s16x8*)&hsrc[j * 8]);
      *(s16x8*)&A1[j * 8] = s0;
    }
    f32x4 c1[2][4];
#pragma unroll
    for (int cg = 0; cg < 2; ++cg)
#pragma unroll
      for (int m = 0; m < 4; ++m) c1[cg][m] = zero4;
    __syncthreads();

    for (int t = 0; t < 20; ++t) {
      const int base_r = (t & 1) * RSZ;
      const int base_w = ((t + 1) & 1) * RSZ;
      s16x8 p[4];
      const bool ld = (t < 19);
      if (ld) {
#pragma unroll
        for (int k = 0; k < 4; ++k)
          p[k] = __builtin_nontemporal_load(
              (const s16x8*)&hsrc[(size_t)(t + 1) * 8192 + (tid + k * 256) * 8]);
      }
#pragma unroll
      for (int cg = 0; cg < 2; ++cg) {
        const int colu = wv * 32 + cg * 16 + (l & 15);
        const int uoff = (16 + (colu >> 3)) * 512 + (colu & 7);
#pragma unroll
        for (int mh = 0; mh < 2; ++mh) {
          f32x4 acc[2][4];
#pragma unroll
          for (int mm = 0; mm < 2; ++mm)
#pragma unroll
            for (int g = 0; g < 4; ++g) acc[mm][g] = zero4;
#pragma unroll
          for (int kc = 0; kc < 8; ++kc) {
            const int ch = kc * 4 + kq;
            s16x8 av[2];
#pragma unroll
            for (int mm = 0; mm < 2; ++mm)
              av[mm] = *(const s16x8*)&A1[base_r + ch * 512 + (mh * 2 + mm) * 128 + la];
#pragma unroll
            for (int g = 0; g < 4; ++g) {
              s16x8 bv = *(const s16x8*)&Wp1[(size_t)ch * 4096 + (g * 128 + colu) * 8];
#pragma unroll
              for (int mm = 0; mm < 2; ++mm)
                acc[mm][g] = __builtin_amdgcn_mfma_f32_16x16x32_bf16(av[mm], bv, acc[mm][g], 0, 0, 0);
            }
          }
          epi2(acc, &c1[cg][mh * 2], bsr[cg], &A1[base_w], uoff, kq, mh,
               nodebase, hfinal, colu, n, t == 19);
        }
      }
      if (ld) {
#pragma unroll
        for (int k = 0; k < 4; ++k)
          *(s16x8*)&A1[base_w + (tid + k * 256) * 8] = p[k];
      }
      __syncthreads();
    }
  }
}

// ---------------------------------------------------------------- MFMA node GEMM
template<int KD, int COLS, bool INBF, bool OUTBF, bool RELU, bool BIAS>
__global__ __launch_bounds__(COLS * 4, 4) void ngemm_m(
    const void* __restrict__ xin_, const u16* __restrict__ Wp,
    const float* __restrict__ b, void* __restrict__ out_, int n)
{
  constexpr int NT = COLS * 4;
  __shared__ __align__(16) u16 A[(KD / 8) * 512];
  const int tid = threadIdx.x;
  const int l = tid & 63;
  const int wq = __builtin_amdgcn_readfirstlane(tid >> 6);
  const int kq = l >> 4;
  const int la = (l & 15) * 8;
  const int colu = wq * 16 + (l & 15);
  const int nodebase = blockIdx.x * 64;

  for (int s = tid; s < 64 * KD / 8; s += NT) {
    int nd = s / (KD / 8), q = s % (KD / 8);
    int gn = min(nodebase + nd, n - 1);
    if (INBF) {
      const u16* xp = (const u16*)xin_ + (size_t)gn * KD + q * 8;
      *(s16x8*)&A[q * 512 + nd * 8] = *(const s16x8*)xp;
    } else {
      const float* xp = (const float*)xin_ + (size_t)gn * KD + q * 8;
      float4 v0 = *(const float4*)xp;
      float4 v1 = *(const float4*)(xp + 4);
      s16x8 pk;
      pk[0] = (short)f2bf(v0.x); pk[1] = (short)f2bf(v0.y);
      pk[2] = (short)f2bf(v0.z); pk[3] = (short)f2bf(v0.w);
      pk[4] = (short)f2bf(v1.x); pk[5] = (short)f2bf(v1.y);
      pk[6] = (short)f2bf(v1.z); pk[7] = (short)f2bf(v1.w);
      *(s16x8*)&A[q * 512 + nd * 8] = pk;
    }
  }
  __syncthreads();

  const f32x4 zero4 = {0.f, 0.f, 0.f, 0.f};
  f32x4 acc[4];
#pragma unroll
  for (int m = 0; m < 4; ++m) acc[m] = zero4;
#pragma unroll
  for (int kc = 0; kc < KD / 32; ++kc) {
    const int ch = kc * 4 + kq;
    s16x8 bv = *(const s16x8*)&Wp[((size_t)ch * COLS + colu) * 8];
#pragma unroll
    for (int m = 0; m < 4; ++m) {
      s16x8 av = *(const s16x8*)&A[ch * 512 + m * 128 + la];
      acc[m] = __builtin_amdgcn_mfma_f32_16x16x32_bf16(av, bv, acc[m], 0, 0, 0);
    }
  }
  float bb = BIAS ? b[colu] : 0.f;
#pragma unroll
  for (int m = 0; m < 4; ++m)
#pragma unroll
    for (int r = 0; r < 4; ++r) {
      int gn = nodebase + m * 16 + kq * 4 + r;
      if (gn < n) {
        float v = acc[m][r] + bb;
        if (RELU) v = fmaxf(v, 0.f);
        if (OUTBF) ((u16*)out_)[(size_t)gn * COLS + colu] = f2bf(v);
        else       ((float*)out_)[(size_t)gn * COLS + colu] = v;
      }
    }
}

// ---------------------------------------------------------------- small utility kernels
__global__ void deg_count(const int* __restrict__ dst, float* __restrict__ deg, int ne, int n) {
  int i = blockIdx.x * 256 + threadIdx.x;
  if (i < ne) {
    int d = dst[i]; d = min(max(d, 0), n - 1);
    atomicAdd(deg + d, 1.f);
  }
}

__global__ void dinv_k(const float* __restrict__ deg, float* __restrict__ dinv, int n) {
  int i = blockIdx.x * 256 + threadIdx.x;
  if (i < n) dinv[i] = rsqrtf(deg[i] + 1.f);
}

// ---- multi-block exclusive scan of (int)deg -> rowptr[0..n] ----
__global__ void scan_part(const float* __restrict__ deg, int* __restrict__ part, int n) {
  __shared__ int sh[256];
  const int tid = threadIdx.x;
  const int base = blockIdx.x * 1024;
  int s = 0;
  for (int j = tid; j < 1024; j += 256) {
    int i = base + j;
    s += (i < n) ? (int)deg[i] : 0;
  }
  sh[tid] = s;
  __syncthreads();
  for (int off = 128; off > 0; off >>= 1) {
    if (tid < off) sh[tid] += sh[tid + off];
    __syncthreads();
  }
  if (tid == 0) part[blockIdx.x] = sh[0];
}

__global__ void scan_exc(int* __restrict__ part, int nb, int* __restrict__ rowptr, int n) {
  __shared__ int sh[256];
  const int tid = threadIdx.x;
  int v = (tid < nb) ? part[tid] : 0;
  sh[tid] = v;
  __syncthreads();
  for (int off = 1; off < 256; off <<= 1) {
    int t = (tid >= off) ? sh[tid - off] : 0;
    __syncthreads();
    sh[tid] += t;
    __syncthreads();
  }
  if (tid < nb) part[tid] = sh[tid] - v;  // exclusive prefix
  if (tid == 255) rowptr[n] = sh[255];    // total
}

__global__ void scan_final(const float* __restrict__ deg, const int* __restrict__ part,
                           int* __restrict__ rowptr, int n) {
  __shared__ int sh[1024];
  const int tid = threadIdx.x;
  const int i = blockIdx.x * 1024 + tid;
  int v = (i < n) ? (int)deg[i] : 0;
  sh[tid] = v;
  __syncthreads();
  for (int off = 1; off < 1024; off <<= 1) {
    int t = (tid >= off) ? sh[tid - off] : 0;
    __syncthreads();
    sh[tid] += t;
    __syncthreads();
  }
  if (i < n) rowptr[i] = part[blockIdx.x] + sh[tid] - v;
}

__global__ void fill_k(const int* __restrict__ src, const int* __restrict__ dst,
                       const int* __restrict__ rowptr, int* __restrict__ cursor,
                       const float* __restrict__ dinv,
                       int* __restrict__ cidx, float* __restrict__ enrm, int ne, int n) {
  int i = blockIdx.x * 256 + threadIdx.x;
  if (i < ne) {
    int s = min(max(src[i], 0), n - 1);
    int d = min(max(dst[i], 0), n - 1);
    int p = atomicAdd(cursor + d, 1);
    int o = rowptr[d] + p;
    cidx[o] = s;
    enrm[o] = dinv[s] * dinv[d];
  }
}

// 128-dim gather on bf16 rows; fp32 accumulate
template<bool OUT32>
__global__ __launch_bounds__(256, 4) void gcn_gather_bf(
    const u16* __restrict__ y, const int* __restrict__ rowptr,
    const int* __restrict__ cidx, const float* __restrict__ enrm,
    const float* __restrict__ dinv, const float* __restrict__ b,
    void* __restrict__ out, int n)
{
  const int l = threadIdx.x & 63;
  const int wq = threadIdx.x >> 6;
  const int node = blockIdx.x * 4 + wq;
  if (node >= n) return;
  float dv = dinv[node];
  unsigned su = ((const unsigned*)(y + (size_t)node * 128))[l];
  float ax = bf2f((u16)(su & 0xffff)) * dv * dv;
  float ay = bf2f((u16)(su >> 16)) * dv * dv;
  int r0 = rowptr[node], r1 = rowptr[node + 1];
  int e = r0;
  for (; e + 1 < r1; e += 2) {
    int s0 = cidx[e], s1 = cidx[e + 1];
    float n0 = enrm[e], n1 = enrm[e + 1];
    unsigned u0 = ((const unsigned*)(y + (size_t)s0 * 128))[l];
    unsigned u1 = ((const unsigned*)(y + (size_t)s1 * 128))[l];
    ax = fmaf(n0, bf2f((u16)(u0 & 0xffff)), ax);
    ay = fmaf(n0, bf2f((u16)(u0 >> 16)), ay);
    ax = fmaf(n1, bf2f((u16)(u1 & 0xffff)), ax);
    ay = fmaf(n1, bf2f((u16)(u1 >> 16)), ay);
  }
  if (e < r1) {
    int s0 = cidx[e];
    float n0 = enrm[e];
    unsigned u0 = ((const unsigned*)(y + (size_t)s0 * 128))[l];
    ax = fmaf(n0, bf2f((u16)(u0 & 0xffff)), ax);
    ay = fmaf(n0, bf2f((u16)(u0 >> 16)), ay);
  }
  float2 bb = *(const float2*)(b + l * 2);
  float ox = fmaxf(ax + bb.x, 0.f);
  float oy = fmaxf(ay + bb.y, 0.f);
  if (OUT32) {
    float2 o; o.x = ox; o.y = oy;
    *(float2*)((float*)out + (size_t)node * 128 + l * 2) = o;
  } else {
    unsigned pk = (unsigned)f2bf(ox) | ((unsigned)f2bf(oy) << 16);
    ((unsigned*)((u16*)out + (size_t)node * 128))[l] = pk;
  }
}

// 64-dim fp32 gather
__global__ __launch_bounds__(256, 4) void gather64_k(
    const float* __restrict__ y, const int* __restrict__ rowptr,
    const int* __restrict__ cidx, const float* __restrict__ enrm,
    const float* __restrict__ dinv, float* __restrict__ out, int n)
{
  const int l = threadIdx.x & 63;
  const int wq = threadIdx.x >> 6;
  const int node = blockIdx.x * 4 + wq;
  if (node >= n) return;
  float dv = dinv[node];
  float acc = y[(size_t)node * 64 + l] * dv * dv;
  int r0 = rowptr[node], r1 = rowptr[node + 1];
  int e = r0;
  for (; e + 1 < r1; e += 2) {
    int s0 = cidx[e], s1 = cidx[e + 1];
    float n0 = enrm[e], n1 = enrm[e + 1];
    acc = fmaf(n0, y[(size_t)s0 * 64 + l], acc);
    acc = fmaf(n1, y[(size_t)s1 * 64 + l], acc);
  }
  if (e < r1) acc = fmaf(enrm[e], y[(size_t)cidx[e] * 64 + l], acc);
  out[(size_t)node * 64 + l] = acc;
}

// ---------------------------------------------------------------- edge head (MFMA)
__global__ __launch_bounds__(256, 4) void edge_head_m(
    const u16* __restrict__ P, const u16* __restrict__ Q,
    const int* __restrict__ src, const int* __restrict__ dst,
    const float* __restrict__ b1, const u16* __restrict__ eW2p,
    const float* __restrict__ b2, const float* __restrict__ eW3,
    const float* __restrict__ b3, float* __restrict__ ep, int ne, int n)
{
  __shared__ __align__(16) u16 H1f[16 * 512];
  __shared__ float Hpart[64][4];
  const int tid = threadIdx.x;
  const int l = tid & 63;
  const int w = __builtin_amdgcn_readfirstlane(tid >> 6);
  const int kq = l >> 4;
  const int la = (l & 15) * 8;
  const int col = w * 16 + (l & 15);
  const int e0 = blockIdx.x * 64;
  {
    int el = tid >> 2, q = tid & 3;
    int e = min(e0 + el, ne - 1);
    int s = min(max(src[e], 0), n - 1);
    int d = min(max(dst[e], 0), n - 1);
    const u16* pr = P + (size_t)s * 128 + q * 32;
    const u16* qr = Q + (size_t)d * 128 + q * 32;
#pragma unroll
    for (int c = 0; c < 4; ++c) {
      s16x8 pv = *(const s16x8*)(pr + c * 8);
      s16x8 qv = *(const s16x8*)(qr + c * 8);
      s16x8 hv;
#pragma unroll
      for (int i = 0; i < 8; ++i) {
        float h = bf2f((u16)pv[i]) + bf2f((u16)qv[i]) + b1[q * 32 + c * 8 + i];
        hv[i] = (short)f2bf(fmaxf(h, 0.f));
      }
      *(s16x8*)&H1f[(q * 4 + c) * 512 + el * 8] = hv;
    }
  }
  __syncthreads();
  const f32x4 zero4 = {0.f, 0.f, 0.f, 0.f};
  f32x4 acc[4];
#pragma unroll
  for (int m = 0; m < 4; ++m) acc[m] = zero4;
#pragma unroll
  for (int kc = 0; kc < 4; ++kc) {
    int ch = kc * 4 + kq;
    s16x8 bv = *(const s16x8*)&eW2p[((size_t)ch * 64 + col) * 8];
#pragma unroll
    for (int m = 0; m < 4; ++m) {
      s16x8 av = *(const s16x8*)&H1f[ch * 512 + m * 128 + la];
      acc[m] = __builtin_amdgcn_mfma_f32_16x16x32_bf16(av, bv, acc[m], 0, 0, 0);
    }
  }
  const float w3 = eW3[col];
  const float b2c = b2[col];
#pragma unroll
  for (int m = 0; m < 4; ++m)
#pragma unroll
    for (int r = 0; r < 4; ++r) {
      float v = fmaxf(acc[m][r] + b2c, 0.f) * w3;
      v += __shfl_xor(v, 1);
      v += __shfl_xor(v, 2);
      v += __shfl_xor(v, 4);
      v += __shfl_xor(v, 8);
      if ((l & 15) == 0) Hpart[m * 16 + kq * 4 + r][w] = v;
    }
  __syncthreads();
  if (tid < 64) {
    float s = Hpart[tid][0] + Hpart[tid][1] + Hpart[tid][2] + Hpart[tid][3] + b3[0];
    int e = e0 + tid;
    if (e < ne) ep[e] = 1.f / (1.f + __expf(-s));
  }
}

// ---------------------------------------------------------------- node heads (MFMA, 2-stage)
__global__ __launch_bounds__(512, 2) void node_heads_m(
    const float* __restrict__ x, const u16* __restrict__ cuW1p,
    const float* __restrict__ cub1, const u16* __restrict__ cuW2p,
    const float* __restrict__ cub2, float* __restrict__ cls,
    float* __restrict__ unc, int n)
{
  __shared__ __align__(16) u16 A[16 * 512];
  __shared__ __align__(16) u16 Hf[16 * 512];
  const int tid = threadIdx.x;
  const int l = tid & 63;
  const int wq = __builtin_amdgcn_readfirstlane(tid >> 6);
  const int kq = l >> 4;
  const int la = (l & 15) * 8;
  const int col = wq * 16 + (l & 15);
  const int nodebase = blockIdx.x * 64;

  for (int s = tid; s < 1024; s += 512) {
    int nd = s >> 4, q = s & 15;
    int gn = min(nodebase + nd, n - 1);
    const float* xp = x + (size_t)gn * 128 + q * 8;
    float4 v0 = *(const float4*)xp;
    float4 v1 = *(const float4*)(xp + 4);
    s16x8 pk;
    pk[0] = (short)f2bf(v0.x); pk[1] = (short)f2bf(v0.y);
    pk[2] = (short)f2bf(v0.z); pk[3] = (short)f2bf(v0.w);
    pk[4] = (short)f2bf(v1.x); pk[5] = (short)f2bf(v1.y);
    pk[6] = (short)f2bf(v1.z); pk[7] = (short)f2bf(v1.w);
    *(s16x8*)&A[q * 512 + nd * 8] = pk;
  }
  __syncthreads();

  const f32x4 zero4 = {0.f, 0.f, 0.f, 0.f};
  f32x4 acc[4];
#pragma unroll
  for (int m = 0; m < 4; ++m) acc[m] = zero4;
#pragma unroll
  for (int kc = 0; kc < 4; ++kc) {
    int ch = kc * 4 + kq;
    s16x8 bv = *(const s16x8*)&cuW1p[((size_t)ch * 128 + col) * 8];
#pragma unroll
    for (int m = 0; m < 4; ++m) {
      s16x8 av = *(const s16x8*)&A[ch * 512 + m * 128 + la];
      acc[m] = __builtin_amdgcn_mfma_f32_16x16x32_bf16(av, bv, acc[m], 0, 0, 0);
    }
  }
  const float bb = cub1[col];
#pragma unroll
  for (int m = 0; m < 4; ++m)
#pragma unroll
    for (int r = 0; r < 4; ++r) {
      float h = fmaxf(acc[m][r] + bb, 0.f);
      int node_r = m * 16 + kq * 4 + r;
      Hf[(col >> 3) * 512 + node_r * 8 + (col & 7)] = f2bf(h);
    }
  __syncthreads();
  if (wq == 0) {
    f32x4 a2[4];
#pragma unroll
    for (int m = 0; m < 4; ++m) a2[m] = zero4;
    const int col2 = l & 15;
#pragma unroll
    for (int kc = 0; kc < 4; ++kc) {
      int ch = kc * 4 + kq;
      s16x8 bv = *(const s16x8*)&cuW2p[((size_t)ch * 16 + col2) * 8];
#pragma unroll
      for (int m = 0; m < 4; ++m) {
        s16x8 av = *(const s16x8*)&Hf[ch * 512 + m * 128 + la];
        a2[m] = __builtin_amdgcn_mfma_f32_16x16x32_bf16(av, bv, a2[m], 0, 0, 0);
      }
    }
    const float b2v = cub2[col2];
#pragma unroll
    for (int m = 0; m < 4; ++m)
#pragma unroll
      for (int r = 0; r < 4; ++r) {
        int node = nodebase + m * 16 + kq * 4 + r;
        if (node < n) {
          float v = a2[m][r] + b2v;
          if (col2 < 4) cls[(size_t)node * 4 + col2] = v;
          else if (col2 == 4) unc[node] = softplus_(v);
        }
      }
  }
}

// ---------------------------------------------------------------- host
extern "C" void kernel_launch(void* const* d_in, const int* in_sizes, int n_in,
                              void* d_out, int out_size, void* d_ws, size_t ws_size,
                              hipStream_t stream)
{
  const float* seq   = (const float*)d_in[0];
  const int*   eidx  = (const int*)d_in[1];
  const float* Wih0  = (const float*)d_in[2];
  const float* Whh0  = (const float*)d_in[3];
  const float* bih0  = (const float*)d_in[4];
  const float* bhh0  = (const float*)d_in[5];
  const float* Wih1  = (const float*)d_in[6];
  const float* Whh1  = (const float*)d_in[7];
  const float* bih1  = (const float*)d_in[8];
  const float* bhh1  = (const float*)d_in[9];
  const float* encW1 = (const float*)d_in[10];
  const float* encb1 = (const float*)d_in[11];
  const float* encW2 = (const float*)d_in[12];
  const float* encb2 = (const float*)d_in[13];
  const float* gW0   = (const float*)d_in[14];
  const float* gb0   = (const float*)d_in[15];
  const float* gW1   = (const float*)d_in[16];
  const float* gb1   = (const float*)d_in[17];
  const float* gW2   = (const float*)d_in[18];
  const float* gb2   = (const float*)d_in[19];
  const float* eW1   = (const float*)d_in[20];
  const float* eb1   = (const float*)d_in[21];
  const float* eW2   = (const float*)d_in[22];
  const float* eb2   = (const float*)d_in[23];
  const float* eW3   = (const float*)d_in[24];
  const float* eb3   = (const float*)d_in[25];
  const float* cW1   = (const float*)d_in[26];
  const float* cb1   = (const float*)d_in[27];
  const float* cW2   = (const float*)d_in[28];
  const float* cb2   = (const float*)d_in[29];
  const float* uW1   = (const float*)d_in[30];
  const float* ub1   = (const float*)d_in[31];
  const float* uW2   = (const float*)d_in[32];
  const float* ub2   = (const float*)d_in[33];

  const int n  = in_sizes[0] / 320;
  const int ne = in_sizes[1] / 2;
  const int* src = eidx;
  const int* dst = eidx + ne;

  char* ws = (char*)d_ws;
  size_t off = 0;
  auto alloc = [&](size_t elems) -> float* {
    float* p = (float*)(ws + off);
    off += ((elems * 4 + 255) & ~(size_t)255);
    return p;
  };
  const size_t nb = (size_t)n * 128;
  float* B1     = alloc(nb);
  float* B2     = alloc(nb);
  float* B4     = alloc(nb);
  float* latent = alloc((size_t)n * 64);
  float* deg    = alloc(n);
  float* dinv   = alloc(n);
  int*   rowptr = (int*)alloc(n + 1);
  int*   cursor = (int*)alloc(n);
  int*   part   = (int*)alloc(256);
  int*   cidx   = (int*)alloc(ne);
  float* enrm   = alloc(ne);
  u16* Wp0    = (u16*)alloc(20 * 512 * 8 / 2);
  u16* Wp1    = (u16*)alloc(32 * 512 * 8 / 2);
  u16* encW1p = (u16*)alloc(128 * 128 / 2);
  u16* encW2p = (u16*)alloc(128 * 64 / 2);
  u16* gW0p   = (u16*)alloc(64 * 128 / 2);
  u16* gW1p   = (u16*)alloc(128 * 128 / 2);
  u16* gW2p   = (u16*)alloc(128 * 128 / 2);
  u16* eW1tp  = (u16*)alloc(128 * 128 / 2);
  u16* eW1bp  = (u16*)alloc(128 * 128 / 2);
  u16* eW2p   = (u16*)alloc(128 * 64 / 2);
  u16* cuW1p  = (u16*)alloc(128 * 128 / 2);
  u16* cuW2p  = (u16*)alloc(1024);
  float* cub1  = alloc(128);
  float* cub2  = alloc(16);
  float* bsum0 = alloc(512);
  float* bsum1 = alloc(512);
  (void)n_in; (void)out_size;

  float* xout = (float*)d_out;
  float* ep   = xout + nb;
  float* cls  = ep + ne;
  float* unc  = cls + (size_t)n * 4;

  auto PK = [&](const float* s, u16* d, int K, int C) {
    pack_w<<<dim3((K * C + 255) / 256), dim3(256), 0, stream>>>(s, d, K, C);
  };
  PK(encW1, encW1p, 128, 128);
  PK(encW2, encW2p, 128, 64);
  PK(gW0,   gW0p,   64, 128);
  PK(gW1,   gW1p,   128, 128);
  PK(gW2,   gW2p,   128, 128);
  PK(eW1,             eW1tp, 128, 128);
  PK(eW1 + 128 * 128, eW1bp, 128, 128);
  PK(eW2,   eW2p,   128, 64);
  pack_headw<<<dim3((128 * 128 + 2048 + 128 + 16 + 255) / 256), dim3(256), 0, stream>>>(
      cW1, cb1, cW2, cb2, uW1, ub1, uW2, ub2, cuW1p, cub1, cuW2p, cub2);

  prep_lstm_w<<<dim3((52 * 512 * 8 + 1024 + 255) / 256), dim3(256), 0, stream>>>(
      Wih0, Whh0, Wih1, Whh1, bih0, bhh0, bih1, bhh1, Wp0, Wp1, bsum0, bsum1);

  // CSR build (multi-block scan)
  hipMemsetAsync(deg, 0, (size_t)n * 4, stream);
  deg_count<<<dim3((ne + 255) / 256), dim3(256), 0, stream>>>(dst, deg, ne, n);
  dinv_k<<<dim3((n + 255) / 256), dim3(256), 0, stream>>>(deg, dinv, n);
  const int nsb = (n + 1023) / 1024;
  scan_part<<<dim3(nsb), dim3(256), 0, stream>>>(deg, part, n);
  scan_exc<<<dim3(1), dim3(256), 0, stream>>>(part, nsb, rowptr, n);
  scan_final<<<dim3(nsb), dim3(1024), 0, stream>>>(deg, part, rowptr, n);
  hipMemsetAsync(cursor, 0, (size_t)n * 4, stream);
  fill_k<<<dim3((ne + 255) / 256), dim3(256), 0, stream>>>(
      src, dst, rowptr, cursor, dinv, cidx, enrm, ne, n);

  const int nblk = (n + 63) / 64;
  const int ntiles = nblk;

  // LSTM: layer-split pipeline, 256-thread blocks (2 independent blocks/CU)
  const size_t per_tile = (size_t)20 * 8192 * sizeof(u16);
  size_t avail = (ws_size > off) ? (ws_size - off) : 0;
  int slab_tiles = (int)((avail / per_tile < (size_t)ntiles) ? (avail / per_tile) : (size_t)ntiles);
  if (slab_tiles < 1) slab_tiles = 1;
  {
    u16* h0seq = (u16*)(ws + off);
    for (int t0 = 0; t0 < ntiles; t0 += slab_tiles) {
      int st = (ntiles - t0 < slab_tiles) ? (ntiles - t0) : slab_tiles;
      int grid = (st < 512) ? st : 512;
      lstm_l0<<<dim3(grid), dim3(256), 0, stream>>>(seq, Wp0, bsum0, h0seq, n, t0, st);
      lstm_l1<<<dim3(grid), dim3(256), 0, stream>>>(h0seq, Wp1, bsum1, B1, n, t0, st);
    }
  }

  u16* t1b = (u16*)B2;
  u16* xb  = (u16*)B1;
  u16* yb  = (u16*)B2;
  u16* xb2 = (u16*)B4;
  u16* Pb  = (u16*)B1;
  u16* Qb  = (u16*)B4;
  // encoder
  ngemm_m<128, 128, false, true, true, true><<<dim3(nblk), dim3(512), 0, stream>>>(B1, encW1p, encb1, t1b, n);
  ngemm_m<128, 64, true, false, false, true><<<dim3(nblk), dim3(256), 0, stream>>>(t1b, encW2p, encb2, latent, n);

  const int gblk = (n + 3) / 4;
  // GCN L0 (reordered)
  gather64_k<<<dim3(gblk), dim3(256), 0, stream>>>(latent, rowptr, cidx, enrm, dinv, B2, n);
  ngemm_m<64, 128, false, true, true, true><<<dim3(nblk), dim3(512), 0, stream>>>(B2, gW0p, gb0, xb, n);
  // GCN L1
  ngemm_m<128, 128, true, true, false, false><<<dim3(nblk), dim3(512), 0, stream>>>(xb, gW1p, nullptr, yb, n);
  gcn_gather_bf<false><<<dim3(gblk), dim3(256), 0, stream>>>(yb, rowptr, cidx, enrm, dinv, gb1, xb2, n);
  // GCN L2
  ngemm_m<128, 128, true, true, false, false><<<dim3(nblk), dim3(512), 0, stream>>>(xb2, gW2p, nullptr, yb, n);
  gcn_gather_bf<true><<<dim3(gblk), dim3(256), 0, stream>>>(yb, rowptr, cidx, enrm, dinv, gb2, xout, n);

  // edge head
  ngemm_m<128, 128, false, true, false, false><<<dim3(nblk), dim3(512), 0, stream>>>(xout, eW1tp, nullptr, Pb, n);
  ngemm_m<128, 128, false, true, false, false><<<dim3(nblk), dim3(512), 0, stream>>>(xout, eW1bp, nullptr, Qb, n);
  edge_head_m<<<dim3((ne + 63) / 64), dim3(256), 0, stream>>>(
      Pb, Qb, src, dst, eb1, eW2p, eb2, eW3, eb3, ep, ne, n);

  node_heads_m<<<dim3(nblk), dim3(512), 0, stream>>>(
      xout, cuW1p, cub1, cuW2p, cub2, cls, unc, n);
}

// Round 16
// 1946.344 us; speedup vs baseline: 1.7118x; 1.7118x over previous
//
#include <hip/hip_runtime.h>
#include <math.h>

typedef float f32x4 __attribute__((ext_vector_type(4)));
typedef short s16x8 __attribute__((ext_vector_type(8)));
typedef unsigned short u16;

// ---------------------------------------------------------------- helpers
__device__ __forceinline__ float sigmoid_(float x) { return 1.f / (1.f + __expf(-x)); }
__device__ __forceinline__ float tanh_(float x) {
  float e = __expf(-2.f * x);
  return fmaf(2.f, 1.f / (1.f + e), -1.f);
}
__device__ __forceinline__ float softplus_(float x) {
  return (x > 15.f) ? x : log1pf(__expf(x));
}
__device__ __forceinline__ u16 f2bf(float f) {  // RNE fp32->bf16
  unsigned u = __float_as_uint(f);
  u += 0x7fffu + ((u >> 16) & 1u);
  return (u16)(u >> 16);
}
__device__ __forceinline__ float bf2f(u16 u) {
  return __uint_as_float((unsigned)u << 16);
}
#define PIN4(x) asm volatile("" : "+v"(x))

// ---------------------------------------------------------------- weight prep
__global__ void prep_lstm_w(const float* __restrict__ Wih0, const float* __restrict__ Whh0,
                            const float* __restrict__ Wih1, const float* __restrict__ Whh1,
                            const float* __restrict__ bih0, const float* __restrict__ bhh0,
                            const float* __restrict__ bih1, const float* __restrict__ bhh1,
                            u16* __restrict__ Wp0, u16* __restrict__ Wp1,
                            float* __restrict__ bs0, float* __restrict__ bs1)
{
  int idx = blockIdx.x * 256 + threadIdx.x;
  if (idx < 20 * 512 * 8) {
    int c = idx >> 12, rem = idx & 4095;
    int col = rem >> 3, e = rem & 7;
    int k = c * 8 + e;
    float v = 0.f;
    if (k < 16) v = Wih0[col * 16 + k];
    else if (k >= 32) v = Whh0[col * 128 + (k - 32)];
    Wp0[idx] = f2bf(v);
  }
  int i1 = idx - 20 * 512 * 8;
  if (i1 >= 0 && i1 < 32 * 512 * 8) {
    int c = i1 >> 12, rem = i1 & 4095;
    int col = rem >> 3, e = rem & 7;
    int k = c * 8 + e;
    float v = (k < 128) ? Wih1[col * 128 + k] : Whh1[col * 128 + (k - 128)];
    Wp1[i1] = f2bf(v);
  }
  int i2 = idx - 52 * 512 * 8;
  if (i2 >= 0 && i2 < 512) bs0[i2] = bih0[i2] + bhh0[i2];
  int i3 = i2 - 512;
  if (i3 >= 0 && i3 < 512) bs1[i3] = bih1[i3] + bhh1[i3];
}

// pack fp32 W[K][C] -> bf16 B-fragments Wp[(k/8)*C + col][8]
__global__ void pack_w(const float* __restrict__ W, u16* __restrict__ Wp, int K, int C) {
  int idx = blockIdx.x * 256 + threadIdx.x;
  if (idx < K * C) {
    int k = idx / C, col = idx % C;
    Wp[((size_t)(k >> 3) * C + col) * 8 + (k & 7)] = f2bf(W[idx]);
  }
}

// pack node-head weights
__global__ void pack_headw(const float* __restrict__ cW1, const float* __restrict__ cb1,
                           const float* __restrict__ cW2, const float* __restrict__ cb2,
                           const float* __restrict__ uW1, const float* __restrict__ ub1,
                           const float* __restrict__ uW2, const float* __restrict__ ub2,
                           u16* __restrict__ cuW1p, float* __restrict__ cub1,
                           u16* __restrict__ cuW2p, float* __restrict__ cub2)
{
  int idx = blockIdx.x * 256 + threadIdx.x;
  if (idx < 128 * 128) {
    int k = idx >> 7, col = idx & 127;
    float v = (col < 64) ? cW1[k * 64 + col] : uW1[k * 64 + (col - 64)];
    cuW1p[((size_t)(k >> 3) * 128 + col) * 8 + (k & 7)] = f2bf(v);
  }
  int j = idx - 128 * 128;
  if (j >= 0 && j < 2048) {
    int ch = j >> 7, rem = j & 127, col = rem >> 3, e = rem & 7;
    int k = ch * 8 + e;
    float v = 0.f;
    if (col < 4 && k < 64) v = cW2[k * 4 + col];
    else if (col == 4 && k >= 64) v = uW2[k - 64];
    cuW2p[j] = f2bf(v);
  }
  int j2 = idx - (128 * 128 + 2048);
  if (j2 >= 0 && j2 < 128) cub1[j2] = (j2 < 64) ? cb1[j2] : ub1[j2 - 64];
  int j3 = j2 - 128;
  if (j3 >= 0 && j3 < 16) cub2[j3] = (j3 < 4) ? cb2[j3] : (j3 == 4 ? ub2[0] : 0.f);
}

// ---------------------------------------------------------------- LSTM epilogue (2 m-groups)
__device__ __forceinline__ void epi2(const f32x4 (&acc)[2][4], f32x4* cs,
    const float (&bs)[4], u16* ldsw, int uoff, int kq, int mh,
    int nodebase, float* hf, int u, int n, bool last)
{
#pragma unroll
  for (int mm = 0; mm < 2; ++mm) {
#pragma unroll
    for (int r = 0; r < 4; ++r) {
      float gi = acc[mm][0][r] + bs[0];
      float gf = acc[mm][1][r] + bs[1];
      float gg = acc[mm][2][r] + bs[2];
      float go = acc[mm][3][r] + bs[3];
      float c = sigmoid_(gf) * cs[mm][r] + sigmoid_(gi) * tanh_(gg);
      cs[mm][r] = c;
      float h = sigmoid_(go) * tanh_(c);
      int node = (mh * 2 + mm) * 16 + kq * 4 + r;
      ldsw[uoff + node * 8] = f2bf(h);
      if (last) {
        int gn = nodebase + node;
        if (gn < n) hf[(size_t)gn * 128 + u] = h;
      }
    }
  }
}

// ---------------------------------------------------------------- LSTM layer 0 (512 thr, known-good)
__global__ __launch_bounds__(512, 2) void lstm_l0(
    const float* __restrict__ seq, const u16* __restrict__ Wp0,
    const float* __restrict__ bs0, u16* __restrict__ h0seq,
    int n, int tile0, int ntiles)
{
  __shared__ __align__(16) u16 A0[2 * 20 * 512];
  const int RSZ = 20 * 512;
  const int tid = threadIdx.x;
  const int l = tid & 63;
  const int wq = __builtin_amdgcn_readfirstlane(tid >> 6);
  const int kq = l >> 4;
  const int la = (l & 15) * 8;
  const int colu = wq * 16 + (l & 15);
  const int uoff = (4 + (colu >> 3)) * 512 + (colu & 7);

  s16x8 b0[5][4];
#pragma unroll
  for (int kc = 0; kc < 5; ++kc)
#pragma unroll
    for (int g = 0; g < 4; ++g) {
      b0[kc][g] = *(const s16x8*)&Wp0[(size_t)(kc * 4 + kq) * 4096 + (g * 128 + colu) * 8];
      PIN4(b0[kc][g]);
    }
  float bsr[4];
#pragma unroll
  for (int g = 0; g < 4; ++g) bsr[g] = bs0[g * 128 + colu];
  const f32x4 zero4 = {0.f, 0.f, 0.f, 0.f};

  for (int tt = blockIdx.x; tt < ntiles; tt += gridDim.x) {
    const int nodebase = (tile0 + tt) * 64;
    const int nld = min(nodebase + (tid >> 2), n - 1);
    u16* __restrict__ hdst = h0seq + (size_t)tt * 20 * 8192;
    for (int i = tid; i < 18 * 512; i += 512) A0[2 * 512 + i] = 0;
    for (int i = tid; i < 2 * 512; i += 512) A0[RSZ + 2 * 512 + i] = 0;
    if (tid < 256) {
      int nd = tid >> 2, q = tid & 3;
      f32x4 v = __builtin_nontemporal_load((const f32x4*)(seq + (size_t)nld * 320 + q * 4));
      unsigned d0 = (unsigned)f2bf(v[0]) | ((unsigned)f2bf(v[1]) << 16);
      unsigned d1 = (unsigned)f2bf(v[2]) | ((unsigned)f2bf(v[3]) << 16);
      unsigned* dstp = (unsigned*)&A0[(q >> 1) * 512 + nd * 8 + (q & 1) * 4];
      dstp[0] = d0; dstp[1] = d1;
    }
    f32x4 c0[4];
#pragma unroll
    for (int m = 0; m < 4; ++m) c0[m] = zero4;
    __syncthreads();

    for (int t = 0; t < 20; ++t) {
      const int base_r = (t & 1) * RSZ;
      const int base_w = ((t + 1) & 1) * RSZ;
      f32x4 xnext;
      const bool ldx = (t < 19) && (tid < 256);
      if (ldx) xnext = __builtin_nontemporal_load(
          (const f32x4*)(seq + (size_t)nld * 320 + (t + 1) * 16 + (tid & 3) * 4));
      if (t >= 1) {
        s16x8 u0 = *(const s16x8*)&A0[base_r + 2048 + tid * 8];
        s16x8 u1 = *(const s16x8*)&A0[base_r + 2048 + 4096 + tid * 8];
        __builtin_nontemporal_store(u0, (s16x8*)&hdst[(size_t)(t - 1) * 8192 + tid * 8]);
        __builtin_nontemporal_store(u1, (s16x8*)&hdst[(size_t)(t - 1) * 8192 + 4096 + tid * 8]);
      }
#pragma unroll
      for (int mh = 0; mh < 2; ++mh) {
        f32x4 acc[2][4];
#pragma unroll
        for (int mm = 0; mm < 2; ++mm)
#pragma unroll
          for (int g = 0; g < 4; ++g) acc[mm][g] = zero4;
#pragma unroll
        for (int kc = 0; kc < 5; ++kc) {
          const int ch = kc * 4 + kq;
          s16x8 av[2];
#pragma unroll
          for (int mm = 0; mm < 2; ++mm)
            av[mm] = *(const s16x8*)&A0[base_r + ch * 512 + (mh * 2 + mm) * 128 + la];
#pragma unroll
          for (int g = 0; g < 4; ++g)
#pragma unroll
            for (int mm = 0; mm < 2; ++mm)
              acc[mm][g] = __builtin_amdgcn_mfma_f32_16x16x32_bf16(av[mm], b0[kc][g], acc[mm][g], 0, 0, 0);
        }
        epi2(acc, &c0[mh * 2], bsr, &A0[base_w], uoff, kq, mh, 0, nullptr, colu, 0, false);
      }
      if (ldx) {
        int nd = tid >> 2, q = tid & 3;
        unsigned d0 = (unsigned)f2bf(xnext[0]) | ((unsigned)f2bf(xnext[1]) << 16);
        unsigned d1 = (unsigned)f2bf(xnext[2]) | ((unsigned)f2bf(xnext[3]) << 16);
        unsigned* dstp = (unsigned*)&A0[base_w + (q >> 1) * 512 + nd * 8 + (q & 1) * 4];
        dstp[0] = d0; dstp[1] = d1;
      }
      __syncthreads();
    }
    {
      s16x8 u0 = *(const s16x8*)&A0[2048 + tid * 8];
      s16x8 u1 = *(const s16x8*)&A0[2048 + 4096 + tid * 8];
      __builtin_nontemporal_store(u0, (s16x8*)&hdst[(size_t)19 * 8192 + tid * 8]);
      __builtin_nontemporal_store(u1, (s16x8*)&hdst[(size_t)19 * 8192 + 4096 + tid * 8]);
    }
    __syncthreads();
  }
}

// ---------------------------------------------------------------- LSTM layer 1 (512 thr, known-good)
__global__ __launch_bounds__(512, 2) void lstm_l1(
    const u16* __restrict__ h0seq, const u16* __restrict__ Wp1,
    const float* __restrict__ bs1, float* __restrict__ hfinal,
    int n, int tile0, int ntiles)
{
  __shared__ __align__(16) u16 A1[2 * 32 * 512];
  const int RSZ = 32 * 512;
  const int tid = threadIdx.x;
  const int l = tid & 63;
  const int wq = __builtin_amdgcn_readfirstlane(tid >> 6);
  const int kq = l >> 4;
  const int la = (l & 15) * 8;
  const int colu = wq * 16 + (l & 15);
  const int uoff = (16 + (colu >> 3)) * 512 + (colu & 7);

  s16x8 b1[8][4];
#pragma unroll
  for (int kc = 0; kc < 8; ++kc)
#pragma unroll
    for (int g = 0; g < 4; ++g) {
      b1[kc][g] = *(const s16x8*)&Wp1[(size_t)(kc * 4 + kq) * 4096 + (g * 128 + colu) * 8];
      PIN4(b1[kc][g]);
    }
  float bsr[4];
#pragma unroll
  for (int g = 0; g < 4; ++g) bsr[g] = bs1[g * 128 + colu];
  const f32x4 zero4 = {0.f, 0.f, 0.f, 0.f};

  for (int tt = blockIdx.x; tt < ntiles; tt += gridDim.x) {
    const int nodebase = (tile0 + tt) * 64;
    const u16* __restrict__ hsrc = h0seq + (size_t)tt * 20 * 8192;
    for (int i = tid; i < 16 * 512; i += 512) A1[16 * 512 + i] = 0;
    {
      s16x8 s0 = __builtin_nontemporal_load((const s16x8*)&hsrc[tid * 8]);
      s16x8 s1 = __builtin_nontemporal_load((const s16x8*)&hsrc[4096 + tid * 8]);
      *(s16x8*)&A1[tid * 8] = s0;
      *(s16x8*)&A1[4096 + tid * 8] = s1;
    }
    f32x4 c1[4];
#pragma unroll
    for (int m = 0; m < 4; ++m) c1[m] = zero4;
    __syncthreads();

    for (int t = 0; t < 20; ++t) {
      const int base_r = (t & 1) * RSZ;
      const int base_w = ((t + 1) & 1) * RSZ;
      s16x8 p0, p1;
      const bool ld = (t < 19);
      if (ld) {
        p0 = __builtin_nontemporal_load((const s16x8*)&hsrc[(size_t)(t + 1) * 8192 + tid * 8]);
        p1 = __builtin_nontemporal_load((const s16x8*)&hsrc[(size_t)(t + 1) * 8192 + 4096 + tid * 8]);
      }
#pragma unroll
      for (int mh = 0; mh < 2; ++mh) {
        f32x4 acc[2][4];
#pragma unroll
        for (int mm = 0; mm < 2; ++mm)
#pragma unroll
          for (int g = 0; g < 4; ++g) acc[mm][g] = zero4;
#pragma unroll
        for (int kc = 0; kc < 8; ++kc) {
          const int ch = kc * 4 + kq;
          s16x8 av[2];
#pragma unroll
          for (int mm = 0; mm < 2; ++mm)
            av[mm] = *(const s16x8*)&A1[base_r + ch * 512 + (mh * 2 + mm) * 128 + la];
#pragma unroll
          for (int g = 0; g < 4; ++g)
#pragma unroll
            for (int mm = 0; mm < 2; ++mm)
              acc[mm][g] = __builtin_amdgcn_mfma_f32_16x16x32_bf16(av[mm], b1[kc][g], acc[mm][g], 0, 0, 0);
        }
        epi2(acc, &c1[mh * 2], bsr, &A1[base_w], uoff, kq, mh, nodebase, hfinal, colu, n, t == 19);
      }
      if (ld) {
        *(s16x8*)&A1[base_w + tid * 8] = p0;
        *(s16x8*)&A1[base_w + 4096 + tid * 8] = p1;
      }
      __syncthreads();
    }
  }
}

// ---------------------------------------------------------------- MFMA node GEMM
template<int KD, int COLS, bool INBF, bool OUTBF, bool RELU, bool BIAS>
__global__ __launch_bounds__(COLS * 4, 4) void ngemm_m(
    const void* __restrict__ xin_, const u16* __restrict__ Wp,
    const float* __restrict__ b, void* __restrict__ out_, int n)
{
  constexpr int NT = COLS * 4;
  __shared__ __align__(16) u16 A[(KD / 8) * 512];
  const int tid = threadIdx.x;
  const int l = tid & 63;
  const int wq = __builtin_amdgcn_readfirstlane(tid >> 6);
  const int kq = l >> 4;
  const int la = (l & 15) * 8;
  const int colu = wq * 16 + (l & 15);
  const int nodebase = blockIdx.x * 64;

  for (int s = tid; s < 64 * KD / 8; s += NT) {
    int nd = s / (KD / 8), q = s % (KD / 8);
    int gn = min(nodebase + nd, n - 1);
    if (INBF) {
      const u16* xp = (const u16*)xin_ + (size_t)gn * KD + q * 8;
      *(s16x8*)&A[q * 512 + nd * 8] = *(const s16x8*)xp;
    } else {
      const float* xp = (const float*)xin_ + (size_t)gn * KD + q * 8;
      float4 v0 = *(const float4*)xp;
      float4 v1 = *(const float4*)(xp + 4);
      s16x8 pk;
      pk[0] = (short)f2bf(v0.x); pk[1] = (short)f2bf(v0.y);
      pk[2] = (short)f2bf(v0.z); pk[3] = (short)f2bf(v0.w);
      pk[4] = (short)f2bf(v1.x); pk[5] = (short)f2bf(v1.y);
      pk[6] = (short)f2bf(v1.z); pk[7] = (short)f2bf(v1.w);
      *(s16x8*)&A[q * 512 + nd * 8] = pk;
    }
  }
  __syncthreads();

  const f32x4 zero4 = {0.f, 0.f, 0.f, 0.f};
  f32x4 acc[4];
#pragma unroll
  for (int m = 0; m < 4; ++m) acc[m] = zero4;
#pragma unroll
  for (int kc = 0; kc < KD / 32; ++kc) {
    const int ch = kc * 4 + kq;
    s16x8 bv = *(const s16x8*)&Wp[((size_t)ch * COLS + colu) * 8];
#pragma unroll
    for (int m = 0; m < 4; ++m) {
      s16x8 av = *(const s16x8*)&A[ch * 512 + m * 128 + la];
      acc[m] = __builtin_amdgcn_mfma_f32_16x16x32_bf16(av, bv, acc[m], 0, 0, 0);
    }
  }
  float bb = BIAS ? b[colu] : 0.f;
#pragma unroll
  for (int m = 0; m < 4; ++m)
#pragma unroll
    for (int r = 0; r < 4; ++r) {
      int gn = nodebase + m * 16 + kq * 4 + r;
      if (gn < n) {
        float v = acc[m][r] + bb;
        if (RELU) v = fmaxf(v, 0.f);
        if (OUTBF) ((u16*)out_)[(size_t)gn * COLS + colu] = f2bf(v);
        else       ((float*)out_)[(size_t)gn * COLS + colu] = v;
      }
    }
}

// ---------------------------------------------------------------- small utility kernels
__global__ void deg_count(const int* __restrict__ dst, float* __restrict__ deg, int ne, int n) {
  int i = blockIdx.x * 256 + threadIdx.x;
  if (i < ne) {
    int d = dst[i]; d = min(max(d, 0), n - 1);
    atomicAdd(deg + d, 1.f);
  }
}

__global__ void dinv_k(const float* __restrict__ deg, float* __restrict__ dinv, int n) {
  int i = blockIdx.x * 256 + threadIdx.x;
  if (i < n) dinv[i] = rsqrtf(deg[i] + 1.f);
}

// ---- multi-block exclusive scan of (int)deg -> rowptr[0..n] ----
__global__ void scan_part(const float* __restrict__ deg, int* __restrict__ part, int n) {
  __shared__ int sh[256];
  const int tid = threadIdx.x;
  const int base = blockIdx.x * 1024;
  int s = 0;
  for (int j = tid; j < 1024; j += 256) {
    int i = base + j;
    s += (i < n) ? (int)deg[i] : 0;
  }
  sh[tid] = s;
  __syncthreads();
  for (int off = 128; off > 0; off >>= 1) {
    if (tid < off) sh[tid] += sh[tid + off];
    __syncthreads();
  }
  if (tid == 0) part[blockIdx.x] = sh[0];
}

__global__ void scan_exc(int* __restrict__ part, int nb, int* __restrict__ rowptr, int n) {
  __shared__ int sh[256];
  const int tid = threadIdx.x;
  int v = (tid < nb) ? part[tid] : 0;
  sh[tid] = v;
  __syncthreads();
  for (int off = 1; off < 256; off <<= 1) {
    int t = (tid >= off) ? sh[tid - off] : 0;
    __syncthreads();
    sh[tid] += t;
    __syncthreads();
  }
  if (tid < nb) part[tid] = sh[tid] - v;  // exclusive prefix
  if (tid == 255) rowptr[n] = sh[255];    // total
}

__global__ void scan_final(const float* __restrict__ deg, const int* __restrict__ part,
                           int* __restrict__ rowptr, int n) {
  __shared__ int sh[1024];
  const int tid = threadIdx.x;
  const int i = blockIdx.x * 1024 + tid;
  int v = (i < n) ? (int)deg[i] : 0;
  sh[tid] = v;
  __syncthreads();
  for (int off = 1; off < 1024; off <<= 1) {
    int t = (tid >= off) ? sh[tid - off] : 0;
    __syncthreads();
    sh[tid] += t;
    __syncthreads();
  }
  if (i < n) rowptr[i] = part[blockIdx.x] + sh[tid] - v;
}

__global__ void fill_k(const int* __restrict__ src, const int* __restrict__ dst,
                       const int* __restrict__ rowptr, int* __restrict__ cursor,
                       const float* __restrict__ dinv,
                       int* __restrict__ cidx, float* __restrict__ enrm, int ne, int n) {
  int i = blockIdx.x * 256 + threadIdx.x;
  if (i < ne) {
    int s = min(max(src[i], 0), n - 1);
    int d = min(max(dst[i], 0), n - 1);
    int p = atomicAdd(cursor + d, 1);
    int o = rowptr[d] + p;
    cidx[o] = s;
    enrm[o] = dinv[s] * dinv[d];
  }
}

// 128-dim gather on bf16 rows; fp32 accumulate
template<bool OUT32>
__global__ __launch_bounds__(256, 4) void gcn_gather_bf(
    const u16* __restrict__ y, const int* __restrict__ rowptr,
    const int* __restrict__ cidx, const float* __restrict__ enrm,
    const float* __restrict__ dinv, const float* __restrict__ b,
    void* __restrict__ out, int n)
{
  const int l = threadIdx.x & 63;
  const int wq = threadIdx.x >> 6;
  const int node = blockIdx.x * 4 + wq;
  if (node >= n) return;
  float dv = dinv[node];
  unsigned su = ((const unsigned*)(y + (size_t)node * 128))[l];
  float ax = bf2f((u16)(su & 0xffff)) * dv * dv;
  float ay = bf2f((u16)(su >> 16)) * dv * dv;
  int r0 = rowptr[node], r1 = rowptr[node + 1];
  int e = r0;
  for (; e + 1 < r1; e += 2) {
    int s0 = cidx[e], s1 = cidx[e + 1];
    float n0 = enrm[e], n1 = enrm[e + 1];
    unsigned u0 = ((const unsigned*)(y + (size_t)s0 * 128))[l];
    unsigned u1 = ((const unsigned*)(y + (size_t)s1 * 128))[l];
    ax = fmaf(n0, bf2f((u16)(u0 & 0xffff)), ax);
    ay = fmaf(n0, bf2f((u16)(u0 >> 16)), ay);
    ax = fmaf(n1, bf2f((u16)(u1 & 0xffff)), ax);
    ay = fmaf(n1, bf2f((u16)(u1 >> 16)), ay);
  }
  if (e < r1) {
    int s0 = cidx[e];
    float n0 = enrm[e];
    unsigned u0 = ((const unsigned*)(y + (size_t)s0 * 128))[l];
    ax = fmaf(n0, bf2f((u16)(u0 & 0xffff)), ax);
    ay = fmaf(n0, bf2f((u16)(u0 >> 16)), ay);
  }
  float2 bb = *(const float2*)(b + l * 2);
  float ox = fmaxf(ax + bb.x, 0.f);
  float oy = fmaxf(ay + bb.y, 0.f);
  if (OUT32) {
    float2 o; o.x = ox; o.y = oy;
    *(float2*)((float*)out + (size_t)node * 128 + l * 2) = o;
  } else {
    unsigned pk = (unsigned)f2bf(ox) | ((unsigned)f2bf(oy) << 16);
    ((unsigned*)((u16*)out + (size_t)node * 128))[l] = pk;
  }
}

// 64-dim fp32 gather
__global__ __launch_bounds__(256, 4) void gather64_k(
    const float* __restrict__ y, const int* __restrict__ rowptr,
    const int* __restrict__ cidx, const float* __restrict__ enrm,
    const float* __restrict__ dinv, float* __restrict__ out, int n)
{
  const int l = threadIdx.x & 63;
  const int wq = threadIdx.x >> 6;
  const int node = blockIdx.x * 4 + wq;
  if (node >= n) return;
  float dv = dinv[node];
  float acc = y[(size_t)node * 64 + l] * dv * dv;
  int r0 = rowptr[node], r1 = rowptr[node + 1];
  int e = r0;
  for (; e + 1 < r1; e += 2) {
    int s0 = cidx[e], s1 = cidx[e + 1];
    float n0 = enrm[e], n1 = enrm[e + 1];
    acc = fmaf(n0, y[(size_t)s0 * 64 + l], acc);
    acc = fmaf(n1, y[(size_t)s1 * 64 + l], acc);
  }
  if (e < r1) acc = fmaf(enrm[e], y[(size_t)cidx[e] * 64 + l], acc);
  out[(size_t)node * 64 + l] = acc;
}

// ---------------------------------------------------------------- edge head (MFMA)
__global__ __launch_bounds__(256, 4) void edge_head_m(
    const u16* __restrict__ P, const u16* __restrict__ Q,
    const int* __restrict__ src, const int* __restrict__ dst,
    const float* __restrict__ b1, const u16* __restrict__ eW2p,
    const float* __restrict__ b2, const float* __restrict__ eW3,
    const float* __restrict__ b3, float* __restrict__ ep, int ne, int n)
{
  __shared__ __align__(16) u16 H1f[16 * 512];
  __shared__ float Hpart[64][4];
  const int tid = threadIdx.x;
  const int l = tid & 63;
  const int w = __builtin_amdgcn_readfirstlane(tid >> 6);
  const int kq = l >> 4;
  const int la = (l & 15) * 8;
  const int col = w * 16 + (l & 15);
  const int e0 = blockIdx.x * 64;
  {
    int el = tid >> 2, q = tid & 3;
    int e = min(e0 + el, ne - 1);
    int s = min(max(src[e], 0), n - 1);
    int d = min(max(dst[e], 0), n - 1);
    const u16* pr = P + (size_t)s * 128 + q * 32;
    const u16* qr = Q + (size_t)d * 128 + q * 32;
#pragma unroll
    for (int c = 0; c < 4; ++c) {
      s16x8 pv = *(const s16x8*)(pr + c * 8);
      s16x8 qv = *(const s16x8*)(qr + c * 8);
      s16x8 hv;
#pragma unroll
      for (int i = 0; i < 8; ++i) {
        float h = bf2f((u16)pv[i]) + bf2f((u16)qv[i]) + b1[q * 32 + c * 8 + i];
        hv[i] = (short)f2bf(fmaxf(h, 0.f));
      }
      *(s16x8*)&H1f[(q * 4 + c) * 512 + el * 8] = hv;
    }
  }
  __syncthreads();
  const f32x4 zero4 = {0.f, 0.f, 0.f, 0.f};
  f32x4 acc[4];
#pragma unroll
  for (int m = 0; m < 4; ++m) acc[m] = zero4;
#pragma unroll
  for (int kc = 0; kc < 4; ++kc) {
    int ch = kc * 4 + kq;
    s16x8 bv = *(const s16x8*)&eW2p[((size_t)ch * 64 + col) * 8];
#pragma unroll
    for (int m = 0; m < 4; ++m) {
      s16x8 av = *(const s16x8*)&H1f[ch * 512 + m * 128 + la];
      acc[m] = __builtin_amdgcn_mfma_f32_16x16x32_bf16(av, bv, acc[m], 0, 0, 0);
    }
  }
  const float w3 = eW3[col];
  const float b2c = b2[col];
#pragma unroll
  for (int m = 0; m < 4; ++m)
#pragma unroll
    for (int r = 0; r < 4; ++r) {
      float v = fmaxf(acc[m][r] + b2c, 0.f) * w3;
      v += __shfl_xor(v, 1);
      v += __shfl_xor(v, 2);
      v += __shfl_xor(v, 4);
      v += __shfl_xor(v, 8);
      if ((l & 15) == 0) Hpart[m * 16 + kq * 4 + r][w] = v;
    }
  __syncthreads();
  if (tid < 64) {
    float s = Hpart[tid][0] + Hpart[tid][1] + Hpart[tid][2] + Hpart[tid][3] + b3[0];
    int e = e0 + tid;
    if (e < ne) ep[e] = 1.f / (1.f + __expf(-s));
  }
}

// ---------------------------------------------------------------- node heads (MFMA, 2-stage)
__global__ __launch_bounds__(512, 2) void node_heads_m(
    const float* __restrict__ x, const u16* __restrict__ cuW1p,
    const float* __restrict__ cub1, const u16* __restrict__ cuW2p,
    const float* __restrict__ cub2, float* __restrict__ cls,
    float* __restrict__ unc, int n)
{
  __shared__ __align__(16) u16 A[16 * 512];
  __shared__ __align__(16) u16 Hf[16 * 512];
  const int tid = threadIdx.x;
  const int l = tid & 63;
  const int wq = __builtin_amdgcn_readfirstlane(tid >> 6);
  const int kq = l >> 4;
  const int la = (l & 15) * 8;
  const int col = wq * 16 + (l & 15);
  const int nodebase = blockIdx.x * 64;

  for (int s = tid; s < 1024; s += 512) {
    int nd = s >> 4, q = s & 15;
    int gn = min(nodebase + nd, n - 1);
    const float* xp = x + (size_t)gn * 128 + q * 8;
    float4 v0 = *(const float4*)xp;
    float4 v1 = *(const float4*)(xp + 4);
    s16x8 pk;
    pk[0] = (short)f2bf(v0.x); pk[1] = (short)f2bf(v0.y);
    pk[2] = (short)f2bf(v0.z); pk[3] = (short)f2bf(v0.w);
    pk[4] = (short)f2bf(v1.x); pk[5] = (short)f2bf(v1.y);
    pk[6] = (short)f2bf(v1.z); pk[7] = (short)f2bf(v1.w);
    *(s16x8*)&A[q * 512 + nd * 8] = pk;
  }
  __syncthreads();

  const f32x4 zero4 = {0.f, 0.f, 0.f, 0.f};
  f32x4 acc[4];
#pragma unroll
  for (int m = 0; m < 4; ++m) acc[m] = zero4;
#pragma unroll
  for (int kc = 0; kc < 4; ++kc) {
    int ch = kc * 4 + kq;
    s16x8 bv = *(const s16x8*)&cuW1p[((size_t)ch * 128 + col) * 8];
#pragma unroll
    for (int m = 0; m < 4; ++m) {
      s16x8 av = *(const s16x8*)&A[ch * 512 + m * 128 + la];
      acc[m] = __builtin_amdgcn_mfma_f32_16x16x32_bf16(av, bv, acc[m], 0, 0, 0);
    }
  }
  const float bb = cub1[col];
#pragma unroll
  for (int m = 0; m < 4; ++m)
#pragma unroll
    for (int r = 0; r < 4; ++r) {
      float h = fmaxf(acc[m][r] + bb, 0.f);
      int node_r = m * 16 + kq * 4 + r;
      Hf[(col >> 3) * 512 + node_r * 8 + (col & 7)] = f2bf(h);
    }
  __syncthreads();
  if (wq == 0) {
    f32x4 a2[4];
#pragma unroll
    for (int m = 0; m < 4; ++m) a2[m] = zero4;
    const int col2 = l & 15;
#pragma unroll
    for (int kc = 0; kc < 4; ++kc) {
      int ch = kc * 4 + kq;
      s16x8 bv = *(const s16x8*)&cuW2p[((size_t)ch * 16 + col2) * 8];
#pragma unroll
      for (int m = 0; m < 4; ++m) {
        s16x8 av = *(const s16x8*)&Hf[ch * 512 + m * 128 + la];
        a2[m] = __builtin_amdgcn_mfma_f32_16x16x32_bf16(av, bv, a2[m], 0, 0, 0);
      }
    }
    const float b2v = cub2[col2];
#pragma unroll
    for (int m = 0; m < 4; ++m)
#pragma unroll
      for (int r = 0; r < 4; ++r) {
        int node = nodebase + m * 16 + kq * 4 + r;
        if (node < n) {
          float v = a2[m][r] + b2v;
          if (col2 < 4) cls[(size_t)node * 4 + col2] = v;
          else if (col2 == 4) unc[node] = softplus_(v);
        }
      }
  }
}

// ---------------------------------------------------------------- host
extern "C" void kernel_launch(void* const* d_in, const int* in_sizes, int n_in,
                              void* d_out, int out_size, void* d_ws, size_t ws_size,
                              hipStream_t stream)
{
  const float* seq   = (const float*)d_in[0];
  const int*   eidx  = (const int*)d_in[1];
  const float* Wih0  = (const float*)d_in[2];
  const float* Whh0  = (const float*)d_in[3];
  const float* bih0  = (const float*)d_in[4];
  const float* bhh0  = (const float*)d_in[5];
  const float* Wih1  = (const float*)d_in[6];
  const float* Whh1  = (const float*)d_in[7];
  const float* bih1  = (const float*)d_in[8];
  const float* bhh1  = (const float*)d_in[9];
  const float* encW1 = (const float*)d_in[10];
  const float* encb1 = (const float*)d_in[11];
  const float* encW2 = (const float*)d_in[12];
  const float* encb2 = (const float*)d_in[13];
  const float* gW0   = (const float*)d_in[14];
  const float* gb0   = (const float*)d_in[15];
  const float* gW1   = (const float*)d_in[16];
  const float* gb1   = (const float*)d_in[17];
  const float* gW2   = (const float*)d_in[18];
  const float* gb2   = (const float*)d_in[19];
  const float* eW1   = (const float*)d_in[20];
  const float* eb1   = (const float*)d_in[21];
  const float* eW2   = (const float*)d_in[22];
  const float* eb2   = (const float*)d_in[23];
  const float* eW3   = (const float*)d_in[24];
  const float* eb3   = (const float*)d_in[25];
  const float* cW1   = (const float*)d_in[26];
  const float* cb1   = (const float*)d_in[27];
  const float* cW2   = (const float*)d_in[28];
  const float* cb2   = (const float*)d_in[29];
  const float* uW1   = (const float*)d_in[30];
  const float* ub1   = (const float*)d_in[31];
  const float* uW2   = (const float*)d_in[32];
  const float* ub2   = (const float*)d_in[33];

  const int n  = in_sizes[0] / 320;
  const int ne = in_sizes[1] / 2;
  const int* src = eidx;
  const int* dst = eidx + ne;

  char* ws = (char*)d_ws;
  size_t off = 0;
  auto alloc = [&](size_t elems) -> float* {
    float* p = (float*)(ws + off);
    off += ((elems * 4 + 255) & ~(size_t)255);
    return p;
  };
  const size_t nb = (size_t)n * 128;
  float* B1     = alloc(nb);
  float* B2     = alloc(nb);
  float* B4     = alloc(nb);
  float* latent = alloc((size_t)n * 64);
  float* deg    = alloc(n);
  float* dinv   = alloc(n);
  int*   rowptr = (int*)alloc(n + 1);
  int*   cursor = (int*)alloc(n);
  int*   part   = (int*)alloc(256);
  int*   cidx   = (int*)alloc(ne);
  float* enrm   = alloc(ne);
  u16* Wp0    = (u16*)alloc(20 * 512 * 8 / 2);
  u16* Wp1    = (u16*)alloc(32 * 512 * 8 / 2);
  u16* encW1p = (u16*)alloc(128 * 128 / 2);
  u16* encW2p = (u16*)alloc(128 * 64 / 2);
  u16* gW0p   = (u16*)alloc(64 * 128 / 2);
  u16* gW1p   = (u16*)alloc(128 * 128 / 2);
  u16* gW2p   = (u16*)alloc(128 * 128 / 2);
  u16* eW1tp  = (u16*)alloc(128 * 128 / 2);
  u16* eW1bp  = (u16*)alloc(128 * 128 / 2);
  u16* eW2p   = (u16*)alloc(128 * 64 / 2);
  u16* cuW1p  = (u16*)alloc(128 * 128 / 2);
  u16* cuW2p  = (u16*)alloc(1024);
  float* cub1  = alloc(128);
  float* cub2  = alloc(16);
  float* bsum0 = alloc(512);
  float* bsum1 = alloc(512);
  (void)n_in; (void)out_size;

  float* xout = (float*)d_out;
  float* ep   = xout + nb;
  float* cls  = ep + ne;
  float* unc  = cls + (size_t)n * 4;

  auto PK = [&](const float* s, u16* d, int K, int C) {
    pack_w<<<dim3((K * C + 255) / 256), dim3(256), 0, stream>>>(s, d, K, C);
  };
  PK(encW1, encW1p, 128, 128);
  PK(encW2, encW2p, 128, 64);
  PK(gW0,   gW0p,   64, 128);
  PK(gW1,   gW1p,   128, 128);
  PK(gW2,   gW2p,   128, 128);
  PK(eW1,             eW1tp, 128, 128);
  PK(eW1 + 128 * 128, eW1bp, 128, 128);
  PK(eW2,   eW2p,   128, 64);
  pack_headw<<<dim3((128 * 128 + 2048 + 128 + 16 + 255) / 256), dim3(256), 0, stream>>>(
      cW1, cb1, cW2, cb2, uW1, ub1, uW2, ub2, cuW1p, cub1, cuW2p, cub2);

  prep_lstm_w<<<dim3((52 * 512 * 8 + 1024 + 255) / 256), dim3(256), 0, stream>>>(
      Wih0, Whh0, Wih1, Whh1, bih0, bhh0, bih1, bhh1, Wp0, Wp1, bsum0, bsum1);

  // CSR build (multi-block scan)
  hipMemsetAsync(deg, 0, (size_t)n * 4, stream);
  deg_count<<<dim3((ne + 255) / 256), dim3(256), 0, stream>>>(dst, deg, ne, n);
  dinv_k<<<dim3((n + 255) / 256), dim3(256), 0, stream>>>(deg, dinv, n);
  const int nsb = (n + 1023) / 1024;
  scan_part<<<dim3(nsb), dim3(256), 0, stream>>>(deg, part, n);
  scan_exc<<<dim3(1), dim3(256), 0, stream>>>(part, nsb, rowptr, n);
  scan_final<<<dim3(nsb), dim3(1024), 0, stream>>>(deg, part, rowptr, n);
  hipMemsetAsync(cursor, 0, (size_t)n * 4, stream);
  fill_k<<<dim3((ne + 255) / 256), dim3(256), 0, stream>>>(
      src, dst, rowptr, cursor, dinv, cidx, enrm, ne, n);

  const int nblk = (n + 63) / 64;
  const int ntiles = nblk;

  // LSTM: layer-split pipeline (512-thread, known-good)
  const size_t per_tile = (size_t)20 * 8192 * sizeof(u16);
  size_t avail = (ws_size > off) ? (ws_size - off) : 0;
  int slab_tiles = (int)((avail / per_tile < (size_t)ntiles) ? (avail / per_tile) : (size_t)ntiles);
  if (slab_tiles < 1) slab_tiles = 1;
  {
    u16* h0seq = (u16*)(ws + off);
    for (int t0 = 0; t0 < ntiles; t0 += slab_tiles) {
      int st = (ntiles - t0 < slab_tiles) ? (ntiles - t0) : slab_tiles;
      int grid = (st < 512) ? st : 512;
      lstm_l0<<<dim3(grid), dim3(512), 0, stream>>>(seq, Wp0, bsum0, h0seq, n, t0, st);
      lstm_l1<<<dim3(grid), dim3(512), 0, stream>>>(h0seq, Wp1, bsum1, B1, n, t0, st);
    }
  }

  u16* t1b = (u16*)B2;
  u16* xb  = (u16*)B1;
  u16* yb  = (u16*)B2;
  u16* xb2 = (u16*)B4;
  u16* Pb  = (u16*)B1;
  u16* Qb  = (u16*)B4;
  // encoder
  ngemm_m<128, 128, false, true, true, true><<<dim3(nblk), dim3(512), 0, stream>>>(B1, encW1p, encb1, t1b, n);
  ngemm_m<128, 64, true, false, false, true><<<dim3(nblk), dim3(256), 0, stream>>>(t1b, encW2p, encb2, latent, n);

  const int gblk = (n + 3) / 4;
  // GCN L0 (reordered)
  gather64_k<<<dim3(gblk), dim3(256), 0, stream>>>(latent, rowptr, cidx, enrm, dinv, B2, n);
  ngemm_m<64, 128, false, true, true, true><<<dim3(nblk), dim3(512), 0, stream>>>(B2, gW0p, gb0, xb, n);
  // GCN L1
  ngemm_m<128, 128, true, true, false, false><<<dim3(nblk), dim3(512), 0, stream>>>(xb, gW1p, nullptr, yb, n);
  gcn_gather_bf<false><<<dim3(gblk), dim3(256), 0, stream>>>(yb, rowptr, cidx, enrm, dinv, gb1, xb2, n);
  // GCN L2
  ngemm_m<128, 128, true, true, false, false><<<dim3(nblk), dim3(512), 0, stream>>>(xb2, gW2p, nullptr, yb, n);
  gcn_gather_bf<true><<<dim3(gblk), dim3(256), 0, stream>>>(yb, rowptr, cidx, enrm, dinv, gb2, xout, n);

  // edge head
  ngemm_m<128, 128, false, true, false, false><<<dim3(nblk), dim3(512), 0, stream>>>(xout, eW1tp, nullptr, Pb, n);
  ngemm_m<128, 128, false, true, false, false><<<dim3(nblk), dim3(512), 0, stream>>>(xout, eW1bp, nullptr, Qb, n);
  edge_head_m<<<dim3((ne + 63) / 64), dim3(256), 0, stream>>>(
      Pb, Qb, src, dst, eb1, eW2p, eb2, eW3, eb3, ep, ne, n);

  node_heads_m<<<dim3(nblk), dim3(512), 0, stream>>>(
      xout, cuW1p, cub1, cuW2p, cub2, cls, unc, n);
}

// Round 17
// 1939.769 us; speedup vs baseline: 1.7177x; 1.0034x over previous
//
#include <hip/hip_runtime.h>
#include <math.h>

typedef float f32x4 __attribute__((ext_vector_type(4)));
typedef short s16x8 __attribute__((ext_vector_type(8)));
typedef unsigned short u16;

// ---------------------------------------------------------------- helpers
__device__ __forceinline__ float sigmoid_(float x) { return 1.f / (1.f + __expf(-x)); }
__device__ __forceinline__ float tanh_(float x) {
  float e = __expf(-2.f * x);
  return fmaf(2.f, 1.f / (1.f + e), -1.f);
}
__device__ __forceinline__ float softplus_(float x) {
  return (x > 15.f) ? x : log1pf(__expf(x));
}
__device__ __forceinline__ u16 f2bf(float f) {  // RNE fp32->bf16
  unsigned u = __float_as_uint(f);
  u += 0x7fffu + ((u >> 16) & 1u);
  return (u16)(u >> 16);
}
__device__ __forceinline__ float bf2f(u16 u) {
  return __uint_as_float((unsigned)u << 16);
}
#define PIN4(x) asm volatile("" : "+v"(x))

// ---------------------------------------------------------------- weight prep
__global__ void prep_lstm_w(const float* __restrict__ Wih0, const float* __restrict__ Whh0,
                            const float* __restrict__ Wih1, const float* __restrict__ Whh1,
                            const float* __restrict__ bih0, const float* __restrict__ bhh0,
                            const float* __restrict__ bih1, const float* __restrict__ bhh1,
                            u16* __restrict__ Wp0, u16* __restrict__ Wp1,
                            float* __restrict__ bs0, float* __restrict__ bs1)
{
  int idx = blockIdx.x * 256 + threadIdx.x;
  if (idx < 20 * 512 * 8) {
    int c = idx >> 12, rem = idx & 4095;
    int col = rem >> 3, e = rem & 7;
    int k = c * 8 + e;
    float v = 0.f;
    if (k < 16) v = Wih0[col * 16 + k];
    else if (k >= 32) v = Whh0[col * 128 + (k - 32)];
    Wp0[idx] = f2bf(v);
  }
  int i1 = idx - 20 * 512 * 8;
  if (i1 >= 0 && i1 < 32 * 512 * 8) {
    int c = i1 >> 12, rem = i1 & 4095;
    int col = rem >> 3, e = rem & 7;
    int k = c * 8 + e;
    float v = (k < 128) ? Wih1[col * 128 + k] : Whh1[col * 128 + (k - 128)];
    Wp1[i1] = f2bf(v);
  }
  int i2 = idx - 52 * 512 * 8;
  if (i2 >= 0 && i2 < 512) bs0[i2] = bih0[i2] + bhh0[i2];
  int i3 = i2 - 512;
  if (i3 >= 0 && i3 < 512) bs1[i3] = bih1[i3] + bhh1[i3];
}

// pack fp32 W[K][C] -> bf16 B-fragments Wp[(k/8)*C + col][8]
__global__ void pack_w(const float* __restrict__ W, u16* __restrict__ Wp, int K, int C) {
  int idx = blockIdx.x * 256 + threadIdx.x;
  if (idx < K * C) {
    int k = idx / C, col = idx % C;
    Wp[((size_t)(k >> 3) * C + col) * 8 + (k & 7)] = f2bf(W[idx]);
  }
}

// pack node-head weights
__global__ void pack_headw(const float* __restrict__ cW1, const float* __restrict__ cb1,
                           const float* __restrict__ cW2, const float* __restrict__ cb2,
                           const float* __restrict__ uW1, const float* __restrict__ ub1,
                           const float* __restrict__ uW2, const float* __restrict__ ub2,
                           u16* __restrict__ cuW1p, float* __restrict__ cub1,
                           u16* __restrict__ cuW2p, float* __restrict__ cub2)
{
  int idx = blockIdx.x * 256 + threadIdx.x;
  if (idx < 128 * 128) {
    int k = idx >> 7, col = idx & 127;
    float v = (col < 64) ? cW1[k * 64 + col] : uW1[k * 64 + (col - 64)];
    cuW1p[((size_t)(k >> 3) * 128 + col) * 8 + (k & 7)] = f2bf(v);
  }
  int j = idx - 128 * 128;
  if (j >= 0 && j < 2048) {
    int ch = j >> 7, rem = j & 127, col = rem >> 3, e = rem & 7;
    int k = ch * 8 + e;
    float v = 0.f;
    if (col < 4 && k < 64) v = cW2[k * 4 + col];
    else if (col == 4 && k >= 64) v = uW2[k - 64];
    cuW2p[j] = f2bf(v);
  }
  int j2 = idx - (128 * 128 + 2048);
  if (j2 >= 0 && j2 < 128) cub1[j2] = (j2 < 64) ? cb1[j2] : ub1[j2 - 64];
  int j3 = j2 - 128;
  if (j3 >= 0 && j3 < 16) cub2[j3] = (j3 < 4) ? cb2[j3] : (j3 == 4 ? ub2[0] : 0.f);
}

// ---------------------------------------------------------------- LSTM epilogue (2 m-groups)
__device__ __forceinline__ void epi2(const f32x4 (&acc)[2][4], f32x4* cs,
    const float (&bs)[4], u16* ldsw, int uoff, int kq, int mh,
    int nodebase, float* hf, int u, int n, bool last)
{
#pragma unroll
  for (int mm = 0; mm < 2; ++mm) {
#pragma unroll
    for (int r = 0; r < 4; ++r) {
      float gi = acc[mm][0][r] + bs[0];
      float gf = acc[mm][1][r] + bs[1];
      float gg = acc[mm][2][r] + bs[2];
      float go = acc[mm][3][r] + bs[3];
      float c = sigmoid_(gf) * cs[mm][r] + sigmoid_(gi) * tanh_(gg);
      cs[mm][r] = c;
      float h = sigmoid_(go) * tanh_(c);
      int node = (mh * 2 + mm) * 16 + kq * 4 + r;
      ldsw[uoff + node * 8] = f2bf(h);
      if (last) {
        int gn = nodebase + node;
        if (gn < n) hf[(size_t)gn * 128 + u] = h;
      }
    }
  }
}

// ---------------------------------------------------------------- LSTM layer 0 (512 thr, known-good)
__global__ __launch_bounds__(512, 2) void lstm_l0(
    const float* __restrict__ seq, const u16* __restrict__ Wp0,
    const float* __restrict__ bs0, u16* __restrict__ h0seq,
    int n, int tile0, int ntiles)
{
  __shared__ __align__(16) u16 A0[2 * 20 * 512];
  const int RSZ = 20 * 512;
  const int tid = threadIdx.x;
  const int l = tid & 63;
  const int wq = __builtin_amdgcn_readfirstlane(tid >> 6);
  const int kq = l >> 4;
  const int la = (l & 15) * 8;
  const int colu = wq * 16 + (l & 15);
  const int uoff = (4 + (colu >> 3)) * 512 + (colu & 7);

  s16x8 b0[5][4];
#pragma unroll
  for (int kc = 0; kc < 5; ++kc)
#pragma unroll
    for (int g = 0; g < 4; ++g) {
      b0[kc][g] = *(const s16x8*)&Wp0[(size_t)(kc * 4 + kq) * 4096 + (g * 128 + colu) * 8];
      PIN4(b0[kc][g]);
    }
  float bsr[4];
#pragma unroll
  for (int g = 0; g < 4; ++g) bsr[g] = bs0[g * 128 + colu];
  const f32x4 zero4 = {0.f, 0.f, 0.f, 0.f};

  for (int tt = blockIdx.x; tt < ntiles; tt += gridDim.x) {
    const int nodebase = (tile0 + tt) * 64;
    const int nld = min(nodebase + (tid >> 2), n - 1);
    u16* __restrict__ hdst = h0seq + (size_t)tt * 20 * 8192;
    for (int i = tid; i < 18 * 512; i += 512) A0[2 * 512 + i] = 0;
    for (int i = tid; i < 2 * 512; i += 512) A0[RSZ + 2 * 512 + i] = 0;
    if (tid < 256) {
      int nd = tid >> 2, q = tid & 3;
      f32x4 v = __builtin_nontemporal_load((const f32x4*)(seq + (size_t)nld * 320 + q * 4));
      unsigned d0 = (unsigned)f2bf(v[0]) | ((unsigned)f2bf(v[1]) << 16);
      unsigned d1 = (unsigned)f2bf(v[2]) | ((unsigned)f2bf(v[3]) << 16);
      unsigned* dstp = (unsigned*)&A0[(q >> 1) * 512 + nd * 8 + (q & 1) * 4];
      dstp[0] = d0; dstp[1] = d1;
    }
    f32x4 c0[4];
#pragma unroll
    for (int m = 0; m < 4; ++m) c0[m] = zero4;
    __syncthreads();

    for (int t = 0; t < 20; ++t) {
      const int base_r = (t & 1) * RSZ;
      const int base_w = ((t + 1) & 1) * RSZ;
      f32x4 xnext;
      const bool ldx = (t < 19) && (tid < 256);
      if (ldx) xnext = __builtin_nontemporal_load(
          (const f32x4*)(seq + (size_t)nld * 320 + (t + 1) * 16 + (tid & 3) * 4));
      if (t >= 1) {
        s16x8 u0 = *(const s16x8*)&A0[base_r + 2048 + tid * 8];
        s16x8 u1 = *(const s16x8*)&A0[base_r + 2048 + 4096 + tid * 8];
        __builtin_nontemporal_store(u0, (s16x8*)&hdst[(size_t)(t - 1) * 8192 + tid * 8]);
        __builtin_nontemporal_store(u1, (s16x8*)&hdst[(size_t)(t - 1) * 8192 + 4096 + tid * 8]);
      }
#pragma unroll
      for (int mh = 0; mh < 2; ++mh) {
        f32x4 acc[2][4];
#pragma unroll
        for (int mm = 0; mm < 2; ++mm)
#pragma unroll
          for (int g = 0; g < 4; ++g) acc[mm][g] = zero4;
#pragma unroll
        for (int kc = 0; kc < 5; ++kc) {
          const int ch = kc * 4 + kq;
          s16x8 av[2];
#pragma unroll
          for (int mm = 0; mm < 2; ++mm)
            av[mm] = *(const s16x8*)&A0[base_r + ch * 512 + (mh * 2 + mm) * 128 + la];
#pragma unroll
          for (int g = 0; g < 4; ++g)
#pragma unroll
            for (int mm = 0; mm < 2; ++mm)
              acc[mm][g] = __builtin_amdgcn_mfma_f32_16x16x32_bf16(av[mm], b0[kc][g], acc[mm][g], 0, 0, 0);
        }
        epi2(acc, &c0[mh * 2], bsr, &A0[base_w], uoff, kq, mh, 0, nullptr, colu, 0, false);
      }
      if (ldx) {
        int nd = tid >> 2, q = tid & 3;
        unsigned d0 = (unsigned)f2bf(xnext[0]) | ((unsigned)f2bf(xnext[1]) << 16);
        unsigned d1 = (unsigned)f2bf(xnext[2]) | ((unsigned)f2bf(xnext[3]) << 16);
        unsigned* dstp = (unsigned*)&A0[base_w + (q >> 1) * 512 + nd * 8 + (q & 1) * 4];
        dstp[0] = d0; dstp[1] = d1;
      }
      __syncthreads();
    }
    {
      s16x8 u0 = *(const s16x8*)&A0[2048 + tid * 8];
      s16x8 u1 = *(const s16x8*)&A0[2048 + 4096 + tid * 8];
      __builtin_nontemporal_store(u0, (s16x8*)&hdst[(size_t)19 * 8192 + tid * 8]);
      __builtin_nontemporal_store(u1, (s16x8*)&hdst[(size_t)19 * 8192 + 4096 + tid * 8]);
    }
    __syncthreads();
  }
}

// ---------------------------------------------------------------- LSTM layer 1 (512 thr, known-good)
__global__ __launch_bounds__(512, 2) void lstm_l1(
    const u16* __restrict__ h0seq, const u16* __restrict__ Wp1,
    const float* __restrict__ bs1, float* __restrict__ hfinal,
    int n, int tile0, int ntiles)
{
  __shared__ __align__(16) u16 A1[2 * 32 * 512];
  const int RSZ = 32 * 512;
  const int tid = threadIdx.x;
  const int l = tid & 63;
  const int wq = __builtin_amdgcn_readfirstlane(tid >> 6);
  const int kq = l >> 4;
  const int la = (l & 15) * 8;
  const int colu = wq * 16 + (l & 15);
  const int uoff = (16 + (colu >> 3)) * 512 + (colu & 7);

  s16x8 b1[8][4];
#pragma unroll
  for (int kc = 0; kc < 8; ++kc)
#pragma unroll
    for (int g = 0; g < 4; ++g) {
      b1[kc][g] = *(const s16x8*)&Wp1[(size_t)(kc * 4 + kq) * 4096 + (g * 128 + colu) * 8];
      PIN4(b1[kc][g]);
    }
  float bsr[4];
#pragma unroll
  for (int g = 0; g < 4; ++g) bsr[g] = bs1[g * 128 + colu];
  const f32x4 zero4 = {0.f, 0.f, 0.f, 0.f};

  for (int tt = blockIdx.x; tt < ntiles; tt += gridDim.x) {
    const int nodebase = (tile0 + tt) * 64;
    const u16* __restrict__ hsrc = h0seq + (size_t)tt * 20 * 8192;
    for (int i = tid; i < 16 * 512; i += 512) A1[16 * 512 + i] = 0;
    {
      s16x8 s0 = __builtin_nontemporal_load((const s16x8*)&hsrc[tid * 8]);
      s16x8 s1 = __builtin_nontemporal_load((const s16x8*)&hsrc[4096 + tid * 8]);
      *(s16x8*)&A1[tid * 8] = s0;
      *(s16x8*)&A1[4096 + tid * 8] = s1;
    }
    f32x4 c1[4];
#pragma unroll
    for (int m = 0; m < 4; ++m) c1[m] = zero4;
    __syncthreads();

    for (int t = 0; t < 20; ++t) {
      const int base_r = (t & 1) * RSZ;
      const int base_w = ((t + 1) & 1) * RSZ;
      s16x8 p0, p1;
      const bool ld = (t < 19);
      if (ld) {
        p0 = __builtin_nontemporal_load((const s16x8*)&hsrc[(size_t)(t + 1) * 8192 + tid * 8]);
        p1 = __builtin_nontemporal_load((const s16x8*)&hsrc[(size_t)(t + 1) * 8192 + 4096 + tid * 8]);
      }
#pragma unroll
      for (int mh = 0; mh < 2; ++mh) {
        f32x4 acc[2][4];
#pragma unroll
        for (int mm = 0; mm < 2; ++mm)
#pragma unroll
          for (int g = 0; g < 4; ++g) acc[mm][g] = zero4;
#pragma unroll
        for (int kc = 0; kc < 8; ++kc) {
          const int ch = kc * 4 + kq;
          s16x8 av[2];
#pragma unroll
          for (int mm = 0; mm < 2; ++mm)
            av[mm] = *(const s16x8*)&A1[base_r + ch * 512 + (mh * 2 + mm) * 128 + la];
#pragma unroll
          for (int g = 0; g < 4; ++g)
#pragma unroll
            for (int mm = 0; mm < 2; ++mm)
              acc[mm][g] = __builtin_amdgcn_mfma_f32_16x16x32_bf16(av[mm], b1[kc][g], acc[mm][g], 0, 0, 0);
        }
        epi2(acc, &c1[mh * 2], bsr, &A1[base_w], uoff, kq, mh, nodebase, hfinal, colu, n, t == 19);
      }
      if (ld) {
        *(s16x8*)&A1[base_w + tid * 8] = p0;
        *(s16x8*)&A1[base_w + 4096 + tid * 8] = p1;
      }
      __syncthreads();
    }
  }
}

// ---------------------------------------------------------------- MFMA node GEMM
template<int KD, int COLS, bool INBF, bool OUTBF, bool RELU, bool BIAS>
__global__ __launch_bounds__(COLS * 4, 4) void ngemm_m(
    const void* __restrict__ xin_, const u16* __restrict__ Wp,
    const float* __restrict__ b, void* __restrict__ out_, int n)
{
  constexpr int NT = COLS * 4;
  __shared__ __align__(16) u16 A[(KD / 8) * 512];
  const int tid = threadIdx.x;
  const int l = tid & 63;
  const int wq = __builtin_amdgcn_readfirstlane(tid >> 6);
  const int kq = l >> 4;
  const int la = (l & 15) * 8;
  const int colu = wq * 16 + (l & 15);
  const int nodebase = blockIdx.x * 64;

  for (int s = tid; s < 64 * KD / 8; s += NT) {
    int nd = s / (KD / 8), q = s % (KD / 8);
    int gn = min(nodebase + nd, n - 1);
    if (INBF) {
      const u16* xp = (const u16*)xin_ + (size_t)gn * KD + q * 8;
      *(s16x8*)&A[q * 512 + nd * 8] = *(const s16x8*)xp;
    } else {
      const float* xp = (const float*)xin_ + (size_t)gn * KD + q * 8;
      float4 v0 = *(const float4*)xp;
      float4 v1 = *(const float4*)(xp + 4);
      s16x8 pk;
      pk[0] = (short)f2bf(v0.x); pk[1] = (short)f2bf(v0.y);
      pk[2] = (short)f2bf(v0.z); pk[3] = (short)f2bf(v0.w);
      pk[4] = (short)f2bf(v1.x); pk[5] = (short)f2bf(v1.y);
      pk[6] = (short)f2bf(v1.z); pk[7] = (short)f2bf(v1.w);
      *(s16x8*)&A[q * 512 + nd * 8] = pk;
    }
  }
  __syncthreads();

  const f32x4 zero4 = {0.f, 0.f, 0.f, 0.f};
  f32x4 acc[4];
#pragma unroll
  for (int m = 0; m < 4; ++m) acc[m] = zero4;
#pragma unroll
  for (int kc = 0; kc < KD / 32; ++kc) {
    const int ch = kc * 4 + kq;
    s16x8 bv = *(const s16x8*)&Wp[((size_t)ch * COLS + colu) * 8];
#pragma unroll
    for (int m = 0; m < 4; ++m) {
      s16x8 av = *(const s16x8*)&A[ch * 512 + m * 128 + la];
      acc[m] = __builtin_amdgcn_mfma_f32_16x16x32_bf16(av, bv, acc[m], 0, 0, 0);
    }
  }
  float bb = BIAS ? b[colu] : 0.f;
#pragma unroll
  for (int m = 0; m < 4; ++m)
#pragma unroll
    for (int r = 0; r < 4; ++r) {
      int gn = nodebase + m * 16 + kq * 4 + r;
      if (gn < n) {
        float v = acc[m][r] + bb;
        if (RELU) v = fmaxf(v, 0.f);
        if (OUTBF) ((u16*)out_)[(size_t)gn * COLS + colu] = f2bf(v);
        else       ((float*)out_)[(size_t)gn * COLS + colu] = v;
      }
    }
}

// ---------------------------------------------------------------- small utility kernels
__global__ void deg_count(const int* __restrict__ dst, float* __restrict__ deg, int ne, int n) {
  int i = blockIdx.x * 256 + threadIdx.x;
  if (i < ne) {
    int d = dst[i]; d = min(max(d, 0), n - 1);
    atomicAdd(deg + d, 1.f);
  }
}

__global__ void dinv_k(const float* __restrict__ deg, float* __restrict__ dinv, int n) {
  int i = blockIdx.x * 256 + threadIdx.x;
  if (i < n) dinv[i] = rsqrtf(deg[i] + 1.f);
}

// ---- multi-block exclusive scan of (int)deg -> rowptr[0..n] ----
__global__ void scan_part(const float* __restrict__ deg, int* __restrict__ part, int n) {
  __shared__ int sh[256];
  const int tid = threadIdx.x;
  const int base = blockIdx.x * 1024;
  int s = 0;
  for (int j = tid; j < 1024; j += 256) {
    int i = base + j;
    s += (i < n) ? (int)deg[i] : 0;
  }
  sh[tid] = s;
  __syncthreads();
  for (int off = 128; off > 0; off >>= 1) {
    if (tid < off) sh[tid] += sh[tid + off];
    __syncthreads();
  }
  if (tid == 0) part[blockIdx.x] = sh[0];
}

__global__ void scan_exc(int* __restrict__ part, int nb, int* __restrict__ rowptr, int n) {
  __shared__ int sh[256];
  const int tid = threadIdx.x;
  int v = (tid < nb) ? part[tid] : 0;
  sh[tid] = v;
  __syncthreads();
  for (int off = 1; off < 256; off <<= 1) {
    int t = (tid >= off) ? sh[tid - off] : 0;
    __syncthreads();
    sh[tid] += t;
    __syncthreads();
  }
  if (tid < nb) part[tid] = sh[tid] - v;
  if (tid == 255) rowptr[n] = sh[255];
}

__global__ void scan_final(const float* __restrict__ deg, const int* __restrict__ part,
                           int* __restrict__ rowptr, int n) {
  __shared__ int sh[1024];
  const int tid = threadIdx.x;
  const int i = blockIdx.x * 1024 + tid;
  int v = (i < n) ? (int)deg[i] : 0;
  sh[tid] = v;
  __syncthreads();
  for (int off = 1; off < 1024; off <<= 1) {
    int t = (tid >= off) ? sh[tid - off] : 0;
    __syncthreads();
    sh[tid] += t;
    __syncthreads();
  }
  if (i < n) rowptr[i] = part[blockIdx.x] + sh[tid] - v;
}

// fill CSR: cidx (src), dnode (dst), eorig (original edge id), enrm
__global__ void fill_k(const int* __restrict__ src, const int* __restrict__ dst,
                       const int* __restrict__ rowptr, int* __restrict__ cursor,
                       const float* __restrict__ dinv,
                       int* __restrict__ cidx, int* __restrict__ dnode,
                       int* __restrict__ eorig, float* __restrict__ enrm, int ne, int n) {
  int i = blockIdx.x * 256 + threadIdx.x;
  if (i < ne) {
    int s = min(max(src[i], 0), n - 1);
    int d = min(max(dst[i], 0), n - 1);
    int p = atomicAdd(cursor + d, 1);
    int o = rowptr[d] + p;
    cidx[o] = s;
    dnode[o] = d;
    eorig[o] = i;
    enrm[o] = dinv[s] * dinv[d];
  }
}

// 128-dim gather on bf16 rows; fp32 accumulate
template<bool OUT32>
__global__ __launch_bounds__(256, 4) void gcn_gather_bf(
    const u16* __restrict__ y, const int* __restrict__ rowptr,
    const int* __restrict__ cidx, const float* __restrict__ enrm,
    const float* __restrict__ dinv, const float* __restrict__ b,
    void* __restrict__ out, int n)
{
  const int l = threadIdx.x & 63;
  const int wq = threadIdx.x >> 6;
  const int node = blockIdx.x * 4 + wq;
  if (node >= n) return;
  float dv = dinv[node];
  unsigned su = ((const unsigned*)(y + (size_t)node * 128))[l];
  float ax = bf2f((u16)(su & 0xffff)) * dv * dv;
  float ay = bf2f((u16)(su >> 16)) * dv * dv;
  int r0 = rowptr[node], r1 = rowptr[node + 1];
  int e = r0;
  for (; e + 1 < r1; e += 2) {
    int s0 = cidx[e], s1 = cidx[e + 1];
    float n0 = enrm[e], n1 = enrm[e + 1];
    unsigned u0 = ((const unsigned*)(y + (size_t)s0 * 128))[l];
    unsigned u1 = ((const unsigned*)(y + (size_t)s1 * 128))[l];
    ax = fmaf(n0, bf2f((u16)(u0 & 0xffff)), ax);
    ay = fmaf(n0, bf2f((u16)(u0 >> 16)), ay);
    ax = fmaf(n1, bf2f((u16)(u1 & 0xffff)), ax);
    ay = fmaf(n1, bf2f((u16)(u1 >> 16)), ay);
  }
  if (e < r1) {
    int s0 = cidx[e];
    float n0 = enrm[e];
    unsigned u0 = ((const unsigned*)(y + (size_t)s0 * 128))[l];
    ax = fmaf(n0, bf2f((u16)(u0 & 0xffff)), ax);
    ay = fmaf(n0, bf2f((u16)(u0 >> 16)), ay);
  }
  float2 bb = *(const float2*)(b + l * 2);
  float ox = fmaxf(ax + bb.x, 0.f);
  float oy = fmaxf(ay + bb.y, 0.f);
  if (OUT32) {
    float2 o; o.x = ox; o.y = oy;
    *(float2*)((float*)out + (size_t)node * 128 + l * 2) = o;
  } else {
    unsigned pk = (unsigned)f2bf(ox) | ((unsigned)f2bf(oy) << 16);
    ((unsigned*)((u16*)out + (size_t)node * 128))[l] = pk;
  }
}

// 64-dim gather on bf16 rows, fp32 out (GCN layer0 reorder)
__global__ __launch_bounds__(256, 4) void gather64_bf(
    const u16* __restrict__ y, const int* __restrict__ rowptr,
    const int* __restrict__ cidx, const float* __restrict__ enrm,
    const float* __restrict__ dinv, float* __restrict__ out, int n)
{
  const int l = threadIdx.x & 63;
  const int wq = threadIdx.x >> 6;
  const int node = blockIdx.x * 4 + wq;
  if (node >= n) return;
  float dv = dinv[node];
  float acc = bf2f(y[(size_t)node * 64 + l]) * dv * dv;
  int r0 = rowptr[node], r1 = rowptr[node + 1];
  int e = r0;
  for (; e + 1 < r1; e += 2) {
    int s0 = cidx[e], s1 = cidx[e + 1];
    float n0 = enrm[e], n1 = enrm[e + 1];
    acc = fmaf(n0, bf2f(y[(size_t)s0 * 64 + l]), acc);
    acc = fmaf(n1, bf2f(y[(size_t)s1 * 64 + l]), acc);
  }
  if (e < r1) acc = fmaf(enrm[e], bf2f(y[(size_t)cidx[e] * 64 + l]), acc);
  out[(size_t)node * 64 + l] = acc;
}

// ---------------------------------------------------------------- edge head (MFMA, CSR-ordered)
// Processes edges in CSR order: dst rows L2/L1-resident; writes ep[eorig[o]].
__global__ __launch_bounds__(256, 4) void edge_head_m(
    const u16* __restrict__ P, const u16* __restrict__ Q,
    const int* __restrict__ cidx, const int* __restrict__ dnode,
    const int* __restrict__ eorig,
    const float* __restrict__ b1, const u16* __restrict__ eW2p,
    const float* __restrict__ b2, const float* __restrict__ eW3,
    const float* __restrict__ b3, float* __restrict__ ep, int ne, int n)
{
  __shared__ __align__(16) u16 H1f[16 * 512];
  __shared__ float Hpart[64][4];
  const int tid = threadIdx.x;
  const int l = tid & 63;
  const int w = __builtin_amdgcn_readfirstlane(tid >> 6);
  const int kq = l >> 4;
  const int la = (l & 15) * 8;
  const int col = w * 16 + (l & 15);
  const int e0 = blockIdx.x * 64;
  {
    int el = tid >> 2, q = tid & 3;
    int o = min(e0 + el, ne - 1);
    int s = cidx[o];
    int d = dnode[o];
    const u16* pr = P + (size_t)s * 128 + q * 32;
    const u16* qr = Q + (size_t)d * 128 + q * 32;
#pragma unroll
    for (int c = 0; c < 4; ++c) {
      s16x8 pv = *(const s16x8*)(pr + c * 8);
      s16x8 qv = *(const s16x8*)(qr + c * 8);
      s16x8 hv;
#pragma unroll
      for (int i = 0; i < 8; ++i) {
        float h = bf2f((u16)pv[i]) + bf2f((u16)qv[i]) + b1[q * 32 + c * 8 + i];
        hv[i] = (short)f2bf(fmaxf(h, 0.f));
      }
      *(s16x8*)&H1f[(q * 4 + c) * 512 + el * 8] = hv;
    }
  }
  __syncthreads();
  const f32x4 zero4 = {0.f, 0.f, 0.f, 0.f};
  f32x4 acc[4];
#pragma unroll
  for (int m = 0; m < 4; ++m) acc[m] = zero4;
#pragma unroll
  for (int kc = 0; kc < 4; ++kc) {
    int ch = kc * 4 + kq;
    s16x8 bv = *(const s16x8*)&eW2p[((size_t)ch * 64 + col) * 8];
#pragma unroll
    for (int m = 0; m < 4; ++m) {
      s16x8 av = *(const s16x8*)&H1f[ch * 512 + m * 128 + la];
      acc[m] = __builtin_amdgcn_mfma_f32_16x16x32_bf16(av, bv, acc[m], 0, 0, 0);
    }
  }
  const float w3 = eW3[col];
  const float b2c = b2[col];
#pragma unroll
  for (int m = 0; m < 4; ++m)
#pragma unroll
    for (int r = 0; r < 4; ++r) {
      float v = fmaxf(acc[m][r] + b2c, 0.f) * w3;
      v += __shfl_xor(v, 1);
      v += __shfl_xor(v, 2);
      v += __shfl_xor(v, 4);
      v += __shfl_xor(v, 8);
      if ((l & 15) == 0) Hpart[m * 16 + kq * 4 + r][w] = v;
    }
  __syncthreads();
  if (tid < 64) {
    int o = e0 + tid;
    if (o < ne) {
      float s = Hpart[tid][0] + Hpart[tid][1] + Hpart[tid][2] + Hpart[tid][3] + b3[0];
      ep[eorig[o]] = 1.f / (1.f + __expf(-s));
    }
  }
}

// ---------------------------------------------------------------- node heads (MFMA, 2-stage)
__global__ __launch_bounds__(512, 2) void node_heads_m(
    const float* __restrict__ x, const u16* __restrict__ cuW1p,
    const float* __restrict__ cub1, const u16* __restrict__ cuW2p,
    const float* __restrict__ cub2, float* __restrict__ cls,
    float* __restrict__ unc, int n)
{
  __shared__ __align__(16) u16 A[16 * 512];
  __shared__ __align__(16) u16 Hf[16 * 512];
  const int tid = threadIdx.x;
  const int l = tid & 63;
  const int wq = __builtin_amdgcn_readfirstlane(tid >> 6);
  const int kq = l >> 4;
  const int la = (l & 15) * 8;
  const int col = wq * 16 + (l & 15);
  const int nodebase = blockIdx.x * 64;

  for (int s = tid; s < 1024; s += 512) {
    int nd = s >> 4, q = s & 15;
    int gn = min(nodebase + nd, n - 1);
    const float* xp = x + (size_t)gn * 128 + q * 8;
    float4 v0 = *(const float4*)xp;
    float4 v1 = *(const float4*)(xp + 4);
    s16x8 pk;
    pk[0] = (short)f2bf(v0.x); pk[1] = (short)f2bf(v0.y);
    pk[2] = (short)f2bf(v0.z); pk[3] = (short)f2bf(v0.w);
    pk[4] = (short)f2bf(v1.x); pk[5] = (short)f2bf(v1.y);
    pk[6] = (short)f2bf(v1.z); pk[7] = (short)f2bf(v1.w);
    *(s16x8*)&A[q * 512 + nd * 8] = pk;
  }
  __syncthreads();

  const f32x4 zero4 = {0.f, 0.f, 0.f, 0.f};
  f32x4 acc[4];
#pragma unroll
  for (int m = 0; m < 4; ++m) acc[m] = zero4;
#pragma unroll
  for (int kc = 0; kc < 4; ++kc) {
    int ch = kc * 4 + kq;
    s16x8 bv = *(const s16x8*)&cuW1p[((size_t)ch * 128 + col) * 8];
#pragma unroll
    for (int m = 0; m < 4; ++m) {
      s16x8 av = *(const s16x8*)&A[ch * 512 + m * 128 + la];
      acc[m] = __builtin_amdgcn_mfma_f32_16x16x32_bf16(av, bv, acc[m], 0, 0, 0);
    }
  }
  const float bb = cub1[col];
#pragma unroll
  for (int m = 0; m < 4; ++m)
#pragma unroll
    for (int r = 0; r < 4; ++r) {
      float h = fmaxf(acc[m][r] + bb, 0.f);
      int node_r = m * 16 + kq * 4 + r;
      Hf[(col >> 3) * 512 + node_r * 8 + (col & 7)] = f2bf(h);
    }
  __syncthreads();
  if (wq == 0) {
    f32x4 a2[4];
#pragma unroll
    for (int m = 0; m < 4; ++m) a2[m] = zero4;
    const int col2 = l & 15;
#pragma unroll
    for (int kc = 0; kc < 4; ++kc) {
      int ch = kc * 4 + kq;
      s16x8 bv = *(const s16x8*)&cuW2p[((size_t)ch * 16 + col2) * 8];
#pragma unroll
      for (int m = 0; m < 4; ++m) {
        s16x8 av = *(const s16x8*)&Hf[ch * 512 + m * 128 + la];
        a2[m] = __builtin_amdgcn_mfma_f32_16x16x32_bf16(av, bv, a2[m], 0, 0, 0);
      }
    }
    const float b2v = cub2[col2];
#pragma unroll
    for (int m = 0; m < 4; ++m)
#pragma unroll
      for (int r = 0; r < 4; ++r) {
        int node = nodebase + m * 16 + kq * 4 + r;
        if (node < n) {
          float v = a2[m][r] + b2v;
          if (col2 < 4) cls[(size_t)node * 4 + col2] = v;
          else if (col2 == 4) unc[node] = softplus_(v);
        }
      }
  }
}

// ---------------------------------------------------------------- host
extern "C" void kernel_launch(void* const* d_in, const int* in_sizes, int n_in,
                              void* d_out, int out_size, void* d_ws, size_t ws_size,
                              hipStream_t stream)
{
  const float* seq   = (const float*)d_in[0];
  const int*   eidx  = (const int*)d_in[1];
  const float* Wih0  = (const float*)d_in[2];
  const float* Whh0  = (const float*)d_in[3];
  const float* bih0  = (const float*)d_in[4];
  const float* bhh0  = (const float*)d_in[5];
  const float* Wih1  = (const float*)d_in[6];
  const float* Whh1  = (const float*)d_in[7];
  const float* bih1  = (const float*)d_in[8];
  const float* bhh1  = (const float*)d_in[9];
  const float* encW1 = (const float*)d_in[10];
  const float* encb1 = (const float*)d_in[11];
  const float* encW2 = (const float*)d_in[12];
  const float* encb2 = (const float*)d_in[13];
  const float* gW0   = (const float*)d_in[14];
  const float* gb0   = (const float*)d_in[15];
  const float* gW1   = (const float*)d_in[16];
  const float* gb1   = (const float*)d_in[17];
  const float* gW2   = (const float*)d_in[18];
  const float* gb2   = (const float*)d_in[19];
  const float* eW1   = (const float*)d_in[20];
  const float* eb1   = (const float*)d_in[21];
  const float* eW2   = (const float*)d_in[22];
  const float* eb2   = (const float*)d_in[23];
  const float* eW3   = (const float*)d_in[24];
  const float* eb3   = (const float*)d_in[25];
  const float* cW1   = (const float*)d_in[26];
  const float* cb1   = (const float*)d_in[27];
  const float* cW2   = (const float*)d_in[28];
  const float* cb2   = (const float*)d_in[29];
  const float* uW1   = (const float*)d_in[30];
  const float* ub1   = (const float*)d_in[31];
  const float* uW2   = (const float*)d_in[32];
  const float* ub2   = (const float*)d_in[33];

  const int n  = in_sizes[0] / 320;
  const int ne = in_sizes[1] / 2;
  const int* src = eidx;
  const int* dst = eidx + ne;

  char* ws = (char*)d_ws;
  size_t off = 0;
  auto alloc = [&](size_t elems) -> float* {
    float* p = (float*)(ws + off);
    off += ((elems * 4 + 255) & ~(size_t)255);
    return p;
  };
  const size_t nb = (size_t)n * 128;
  float* B1     = alloc(nb);
  float* B2     = alloc(nb);
  float* B4     = alloc(nb);
  float* latent = alloc((size_t)n * 32);   // bf16 [n][64]
  float* deg    = alloc(n);
  float* dinv   = alloc(n);
  int*   rowptr = (int*)alloc(n + 1);
  int*   cursor = (int*)alloc(n);
  int*   part   = (int*)alloc(256);
  int*   cidx   = (int*)alloc(ne);
  int*   dnode  = (int*)alloc(ne);
  int*   eorig  = (int*)alloc(ne);
  float* enrm   = alloc(ne);
  u16* Wp0    = (u16*)alloc(20 * 512 * 8 / 2);
  u16* Wp1    = (u16*)alloc(32 * 512 * 8 / 2);
  u16* encW1p = (u16*)alloc(128 * 128 / 2);
  u16* encW2p = (u16*)alloc(128 * 64 / 2);
  u16* gW0p   = (u16*)alloc(64 * 128 / 2);
  u16* gW1p   = (u16*)alloc(128 * 128 / 2);
  u16* gW2p   = (u16*)alloc(128 * 128 / 2);
  u16* eW1tp  = (u16*)alloc(128 * 128 / 2);
  u16* eW1bp  = (u16*)alloc(128 * 128 / 2);
  u16* eW2p   = (u16*)alloc(128 * 64 / 2);
  u16* cuW1p  = (u16*)alloc(128 * 128 / 2);
  u16* cuW2p  = (u16*)alloc(1024);
  float* cub1  = alloc(128);
  float* cub2  = alloc(16);
  float* bsum0 = alloc(512);
  float* bsum1 = alloc(512);
  (void)n_in; (void)out_size;

  float* xout = (float*)d_out;
  float* ep   = xout + nb;
  float* cls  = ep + ne;
  float* unc  = cls + (size_t)n * 4;

  auto PK = [&](const float* s, u16* d, int K, int C) {
    pack_w<<<dim3((K * C + 255) / 256), dim3(256), 0, stream>>>(s, d, K, C);
  };
  PK(encW1, encW1p, 128, 128);
  PK(encW2, encW2p, 128, 64);
  PK(gW0,   gW0p,   64, 128);
  PK(gW1,   gW1p,   128, 128);
  PK(gW2,   gW2p,   128, 128);
  PK(eW1,             eW1tp, 128, 128);
  PK(eW1 + 128 * 128, eW1bp, 128, 128);
  PK(eW2,   eW2p,   128, 64);
  pack_headw<<<dim3((128 * 128 + 2048 + 128 + 16 + 255) / 256), dim3(256), 0, stream>>>(
      cW1, cb1, cW2, cb2, uW1, ub1, uW2, ub2, cuW1p, cub1, cuW2p, cub2);

  prep_lstm_w<<<dim3((52 * 512 * 8 + 1024 + 255) / 256), dim3(256), 0, stream>>>(
      Wih0, Whh0, Wih1, Whh1, bih0, bhh0, bih1, bhh1, Wp0, Wp1, bsum0, bsum1);

  // CSR build (multi-block scan)
  hipMemsetAsync(deg, 0, (size_t)n * 4, stream);
  deg_count<<<dim3((ne + 255) / 256), dim3(256), 0, stream>>>(dst, deg, ne, n);
  dinv_k<<<dim3((n + 255) / 256), dim3(256), 0, stream>>>(deg, dinv, n);
  const int nsb = (n + 1023) / 1024;
  scan_part<<<dim3(nsb), dim3(256), 0, stream>>>(deg, part, n);
  scan_exc<<<dim3(1), dim3(256), 0, stream>>>(part, nsb, rowptr, n);
  scan_final<<<dim3(nsb), dim3(1024), 0, stream>>>(deg, part, rowptr, n);
  hipMemsetAsync(cursor, 0, (size_t)n * 4, stream);
  fill_k<<<dim3((ne + 255) / 256), dim3(256), 0, stream>>>(
      src, dst, rowptr, cursor, dinv, cidx, dnode, eorig, enrm, ne, n);

  const int nblk = (n + 63) / 64;
  const int ntiles = nblk;

  // LSTM: layer-split pipeline (512-thread, known-good)
  const size_t per_tile = (size_t)20 * 8192 * sizeof(u16);
  size_t avail = (ws_size > off) ? (ws_size - off) : 0;
  int slab_tiles = (int)((avail / per_tile < (size_t)ntiles) ? (avail / per_tile) : (size_t)ntiles);
  if (slab_tiles < 1) slab_tiles = 1;
  {
    u16* h0seq = (u16*)(ws + off);
    for (int t0 = 0; t0 < ntiles; t0 += slab_tiles) {
      int st = (ntiles - t0 < slab_tiles) ? (ntiles - t0) : slab_tiles;
      int grid = (st < 512) ? st : 512;
      lstm_l0<<<dim3(grid), dim3(512), 0, stream>>>(seq, Wp0, bsum0, h0seq, n, t0, st);
      lstm_l1<<<dim3(grid), dim3(512), 0, stream>>>(h0seq, Wp1, bsum1, B1, n, t0, st);
    }
  }

  u16* t1b  = (u16*)B2;
  u16* latb = (u16*)latent;   // bf16 [n][64]
  u16* xb   = (u16*)B1;
  u16* yb   = (u16*)B2;
  u16* xb2  = (u16*)B4;
  u16* Pb   = (u16*)B1;
  u16* Qb   = (u16*)B4;
  // encoder: hf(fp32, B1) -> t1b(bf16, B2) -> latb(bf16)
  ngemm_m<128, 128, false, true, true, true><<<dim3(nblk), dim3(512), 0, stream>>>(B1, encW1p, encb1, t1b, n);
  ngemm_m<128, 64, true, true, false, true><<<dim3(nblk), dim3(256), 0, stream>>>(t1b, encW2p, encb2, latb, n);

  const int gblk = (n + 3) / 4;
  // GCN L0 (reordered): aggregate latent (64, bf16 rows, fp32 acc) -> B2 fp32, GEMM bias+relu -> xb
  gather64_bf<<<dim3(gblk), dim3(256), 0, stream>>>(latb, rowptr, cidx, enrm, dinv, B2, n);
  ngemm_m<64, 128, false, true, true, true><<<dim3(nblk), dim3(512), 0, stream>>>(B2, gW0p, gb0, xb, n);
  // GCN L1
  ngemm_m<128, 128, true, true, false, false><<<dim3(nblk), dim3(512), 0, stream>>>(xb, gW1p, nullptr, yb, n);
  gcn_gather_bf<false><<<dim3(gblk), dim3(256), 0, stream>>>(yb, rowptr, cidx, enrm, dinv, gb1, xb2, n);
  // GCN L2
  ngemm_m<128, 128, true, true, false, false><<<dim3(nblk), dim3(512), 0, stream>>>(xb2, gW2p, nullptr, yb, n);
  gcn_gather_bf<true><<<dim3(gblk), dim3(256), 0, stream>>>(yb, rowptr, cidx, enrm, dinv, gb2, xout, n);

  // edge head: P/Q bf16 precompute + CSR-ordered MFMA head
  ngemm_m<128, 128, false, true, false, false><<<dim3(nblk), dim3(512), 0, stream>>>(xout, eW1tp, nullptr, Pb, n);
  ngemm_m<128, 128, false, true, false, false><<<dim3(nblk), dim3(512), 0, stream>>>(xout, eW1bp, nullptr, Qb, n);
  edge_head_m<<<dim3((ne + 63) / 64), dim3(256), 0, stream>>>(
      Pb, Qb, cidx, dnode, eorig, eb1, eW2p, eb2, eW3, eb3, ep, ne, n);

  node_heads_m<<<dim3(nblk), dim3(512), 0, stream>>>(
      xout, cuW1p, cub1, cuW2p, cub2, cls, unc, n);
}